// Round 8
// baseline (217.063 us; speedup 1.0000x reference)
//
#include <hip/hip_runtime.h>
#include <hip/hip_bf16.h>

#define NNODES 30000
#define NEDGES 480000
#define TE (NEDGES + NNODES)   // edges incl. self-loops
#define FH 256                 // hidden width (H*C)
#define NH 8                   // heads
#define NSB ((NNODES + 255) / 256)   // scan blocks = 118

typedef unsigned short ushort_t;
typedef __attribute__((ext_vector_type(8))) _Float16 f16x8;
typedef __attribute__((ext_vector_type(2))) _Float16 f16x2;
typedef __attribute__((ext_vector_type(4))) float f32x4;

// ---------------- CSR build (dst-sorted src lists) ----------------
__global__ void count_kernel(const int* __restrict__ ei, int* __restrict__ counts) {
    int e = blockIdx.x * 256 + threadIdx.x;
    if (e >= TE) return;
    int d = (e < NEDGES) ? ei[NEDGES + e] : (e - NEDGES);
    atomicAdd(&counts[d], 1);
}

// hierarchical scan: (1) per-block local exclusive scan + block sums
__global__ __launch_bounds__(256) void scan1_kernel(const int* __restrict__ counts,
                                                    int* __restrict__ rp,
                                                    int* __restrict__ bsum) {
    __shared__ int s[256];
    const int tid = threadIdx.x;
    const int i = blockIdx.x * 256 + tid;
    int v = (i < NNODES) ? counts[i] : 0;
    s[tid] = v;
    __syncthreads();
    for (int off = 1; off < 256; off <<= 1) {
        int t = (tid >= off) ? s[tid - off] : 0;
        __syncthreads();
        s[tid] += t;
        __syncthreads();
    }
    if (i < NNODES) rp[i] = s[tid] - v;          // local exclusive prefix
    if (tid == 255) bsum[blockIdx.x] = s[255];
}

// (2) scan the 118 block sums in place (exclusive)
__global__ __launch_bounds__(128) void scan2_kernel(int* __restrict__ bsum) {
    __shared__ int s[128];
    const int tid = threadIdx.x;
    int v = (tid < NSB) ? bsum[tid] : 0;
    s[tid] = v;
    __syncthreads();
    for (int off = 1; off < 128; off <<= 1) {
        int t = (tid >= off) ? s[tid - off] : 0;
        __syncthreads();
        s[tid] += t;
        __syncthreads();
    }
    if (tid < NSB) bsum[tid] = s[tid] - v;
}

// (3) add block offsets, fan out to rp/cursor
__global__ __launch_bounds__(256) void scan3_kernel(int* __restrict__ rp,
                                                    const int* __restrict__ bsum,
                                                    int* __restrict__ cursor) {
    const int i = blockIdx.x * 256 + threadIdx.x;
    if (i < NNODES) {
        int r = rp[i] + bsum[blockIdx.x];
        rp[i] = r;
        cursor[i] = r;
    }
    if (i == 0) rp[NNODES] = TE;   // total is a compile-time constant
}

__global__ void fill_kernel(const int* __restrict__ ei, int* __restrict__ cursor,
                            int* __restrict__ ssrc) {
    int e = blockIdx.x * 256 + threadIdx.x;
    if (e >= TE) return;
    int s, d;
    if (e < NEDGES) { s = ei[e]; d = ei[NEDGES + e]; }
    else            { s = e - NEDGES; d = s; }
    int pos = atomicAdd(&cursor[d], 1);
    ssrc[pos] = s;
}

// ---------------- fp16 helpers ----------------
__device__ __forceinline__ unsigned f2h2(float a, float b) {  // pack 2 floats
    f16x2 h;
    h.x = (_Float16)a;
    h.y = (_Float16)b;
    return __builtin_bit_cast(unsigned, h);
}

// ---------------- prepass: fp32 -> fp16 ----------------
__global__ void cvt_x_kernel(const float* __restrict__ X,
                             _Float16* __restrict__ out, int nquads) {
    int i = blockIdx.x * 256 + threadIdx.x;
    if (i >= nquads) return;
    float4 v = *reinterpret_cast<const float4*>(&X[(size_t)i * 4]);
    uint2 st;
    st.x = f2h2(v.x, v.y);
    st.y = f2h2(v.z, v.w);
    *reinterpret_cast<uint2*>(&out[(size_t)i * 4]) = st;
}

// W [K][256] row-major -> Wt fp16 [256][K] (n-major)
template<int K>
__global__ void cvtT_w(const float* __restrict__ W, _Float16* __restrict__ t) {
    int idx = blockIdx.x * 256 + threadIdx.x;   // n fast -> coalesced read
    if (idx >= 256 * K) return;
    int n = idx & 255, k = idx >> 8;
    t[n * K + k] = (_Float16)W[idx];
}

// ---------------- fp16 MFMA GEMM (h = X @ W) + fused alpha dots ----------------
// BM=128 x BN=128, BK=32, 256 threads = 4 waves of 64x64 (4x4 frags 16x16x32).
template<int K>
__global__ __launch_bounds__(256) void gemm_mfma(
    const _Float16* __restrict__ A,  const _Float16* __restrict__ Bt,   // [M][K], [256][K]
    const float* __restrict__ ASRC, const float* __restrict__ ADST,
    _Float16* __restrict__ HFh, float* __restrict__ AS, float* __restrict__ AD) {

    constexpr int LDK = 40;   // pad: 80B row stride, 16B aligned chunks
    __shared__ _Float16 Ah[128][LDK], Bh[128][LDK];   // 20 KB total

    const int tid  = threadIdx.x;
    const int lane = tid & 63;
    const int wid  = tid >> 6;
    const int m0 = blockIdx.x * 128;
    const int n0 = blockIdx.y * 128;
    const int wm = (wid & 1) * 64, wn = (wid >> 1) * 64;
    const int q = lane >> 4;          // quarter-wave
    const int c = lane & 15;

    f32x4 acc[4][4];
#pragma unroll
    for (int mi = 0; mi < 4; ++mi)
#pragma unroll
        for (int ni = 0; ni < 4; ++ni) acc[mi][ni] = (f32x4){0.f, 0.f, 0.f, 0.f};

    for (int k0 = 0; k0 < K; k0 += 32) {
        __syncthreads();
#pragma unroll
        for (int rep = 0; rep < 2; ++rep) {
            int idx = tid + 256 * rep;          // 0..511
            int row = idx >> 2;                 // 0..127
            int ch  = (idx & 3) * 8;            // k-chunk of 8 halves
            int gr = m0 + row;
            uint4 v = make_uint4(0u, 0u, 0u, 0u);
            if (gr < NNODES)
                v = *reinterpret_cast<const uint4*>(&A[(size_t)gr * K + k0 + ch]);
            *reinterpret_cast<uint4*>(&Ah[row][ch]) = v;
            uint4 bv = *reinterpret_cast<const uint4*>(&Bt[(size_t)(n0 + row) * K + k0 + ch]);
            *reinterpret_cast<uint4*>(&Bh[row][ch]) = bv;
        }
        __syncthreads();

        const int koff = q * 8;
        f16x8 fa[4], fb[4];
#pragma unroll
        for (int mi = 0; mi < 4; ++mi)
            fa[mi] = *reinterpret_cast<const f16x8*>(&Ah[wm + mi * 16 + c][koff]);
#pragma unroll
        for (int ni = 0; ni < 4; ++ni)
            fb[ni] = *reinterpret_cast<const f16x8*>(&Bh[wn + ni * 16 + c][koff]);
#pragma unroll
        for (int mi = 0; mi < 4; ++mi)
#pragma unroll
            for (int ni = 0; ni < 4; ++ni)
                acc[mi][ni] = __builtin_amdgcn_mfma_f32_16x16x32_f16(fa[mi], fb[ni], acc[mi][ni], 0, 0, 0);
    }

    // ---- epilogue: h (fp16) stores + fused per-head alpha dots (fp32 acc) ----
    float as_v[4], ad_v[4];
#pragma unroll
    for (int ni = 0; ni < 4; ++ni) {
        as_v[ni] = ASRC[n0 + wn + ni * 16 + c];
        ad_v[ni] = ADST[n0 + wn + ni * 16 + c];
    }
    const int head0 = (n0 + wn) >> 5;   // this wave covers heads head0, head0+1

#pragma unroll
    for (int mi = 0; mi < 4; ++mi) {
#pragma unroll
        for (int j = 0; j < 4; ++j) {
            int row = m0 + wm + mi * 16 + q * 4 + j;
            bool ok = row < NNODES;
            if (ok) {
#pragma unroll
                for (int ni = 0; ni < 4; ++ni)
                    HFh[(size_t)row * FH + n0 + wn + ni * 16 + c] = (_Float16)acc[mi][ni][j];
            }
            float ps0 = acc[mi][0][j] * as_v[0] + acc[mi][1][j] * as_v[1];
            float ps1 = acc[mi][2][j] * as_v[2] + acc[mi][3][j] * as_v[3];
            float pd0 = acc[mi][0][j] * ad_v[0] + acc[mi][1][j] * ad_v[1];
            float pd1 = acc[mi][2][j] * ad_v[2] + acc[mi][3][j] * ad_v[3];
#pragma unroll
            for (int off = 8; off >= 1; off >>= 1) {
                ps0 += __shfl_xor(ps0, off);
                ps1 += __shfl_xor(ps1, off);
                pd0 += __shfl_xor(pd0, off);
                pd1 += __shfl_xor(pd1, off);
            }
            if (ok && c == 0) {
                AS[row * NH + head0]     = ps0;
                AS[row * NH + head0 + 1] = ps1;
                AD[row * NH + head0]     = pd0;
                AD[row * NH + head0 + 1] = pd1;
            }
        }
    }
}

// ---------------- per-edge normalized attention weights ----------------
// One wave per node, one lane per edge (fast path deg<=64; generic 2-pass
// fallback). Stores alpha[pos][8] fp32, pre-divided by the per-head denom.
__global__ __launch_bounds__(256) void alpha_kernel(
    const float* __restrict__ AS, const float* __restrict__ AD,
    const int* __restrict__ rp, const int* __restrict__ ssrc,
    float* __restrict__ ALPHA) {

    const int tid  = threadIdx.x;
    const int lane = tid & 63;
    const int node = __builtin_amdgcn_readfirstlane(blockIdx.x * 4 + (tid >> 6));

    const int p0  = rp[node];
    const int deg = rp[node + 1] - p0;   // >= 1 (self-loop)

    const float4 ad0 = *reinterpret_cast<const float4*>(&AD[node * NH]);
    const float4 ad1 = *reinterpret_cast<const float4*>(&AD[node * NH + 4]);

    if (deg <= 64) {
        float w[8];
#pragma unroll
        for (int h = 0; h < 8; ++h) w[h] = 0.f;
        if (lane < deg) {
            int s = ssrc[p0 + lane];
            float4 as0 = *reinterpret_cast<const float4*>(&AS[s * NH]);
            float4 as1 = *reinterpret_cast<const float4*>(&AS[s * NH + 4]);
            float sv[8] = {as0.x + ad0.x, as0.y + ad0.y, as0.z + ad0.z, as0.w + ad0.w,
                           as1.x + ad1.x, as1.y + ad1.y, as1.z + ad1.z, as1.w + ad1.w};
#pragma unroll
            for (int h = 0; h < 8; ++h) {
                float t = sv[h] > 0.f ? sv[h] : 0.2f * sv[h];
                w[h] = __expf(t);
            }
        }
        float den[8];
#pragma unroll
        for (int h = 0; h < 8; ++h) {
            den[h] = w[h];
#pragma unroll
            for (int off = 32; off >= 1; off >>= 1)
                den[h] += __shfl_xor(den[h], off);
        }
        if (lane < deg) {
            float4 o0, o1;
            o0.x = w[0] / (den[0] + 1e-16f); o0.y = w[1] / (den[1] + 1e-16f);
            o0.z = w[2] / (den[2] + 1e-16f); o0.w = w[3] / (den[3] + 1e-16f);
            o1.x = w[4] / (den[4] + 1e-16f); o1.y = w[5] / (den[5] + 1e-16f);
            o1.z = w[6] / (den[6] + 1e-16f); o1.w = w[7] / (den[7] + 1e-16f);
            *reinterpret_cast<float4*>(&ALPHA[(size_t)(p0 + lane) * NH])     = o0;
            *reinterpret_cast<float4*>(&ALPHA[(size_t)(p0 + lane) * NH + 4]) = o1;
        }
    } else {
        // generic: pass 1 stores raw w + accumulates den; pass 2 rescales
        float den[8];
#pragma unroll
        for (int h = 0; h < 8; ++h) den[h] = 0.f;
        for (int e = lane; e < deg; e += 64) {
            int s = ssrc[p0 + e];
            float4 as0 = *reinterpret_cast<const float4*>(&AS[s * NH]);
            float4 as1 = *reinterpret_cast<const float4*>(&AS[s * NH + 4]);
            float sv[8] = {as0.x + ad0.x, as0.y + ad0.y, as0.z + ad0.z, as0.w + ad0.w,
                           as1.x + ad1.x, as1.y + ad1.y, as1.z + ad1.z, as1.w + ad1.w};
            float w[8];
#pragma unroll
            for (int h = 0; h < 8; ++h) {
                float t = sv[h] > 0.f ? sv[h] : 0.2f * sv[h];
                w[h] = __expf(t);
                den[h] += w[h];
            }
            *reinterpret_cast<float4*>(&ALPHA[(size_t)(p0 + e) * NH])     = make_float4(w[0], w[1], w[2], w[3]);
            *reinterpret_cast<float4*>(&ALPHA[(size_t)(p0 + e) * NH + 4]) = make_float4(w[4], w[5], w[6], w[7]);
        }
#pragma unroll
        for (int h = 0; h < 8; ++h) {
#pragma unroll
            for (int off = 32; off >= 1; off >>= 1)
                den[h] += __shfl_xor(den[h], off);
            den[h] = 1.f / (den[h] + 1e-16f);
        }
        for (int e = lane; e < deg; e += 64) {
            float4 w0 = *reinterpret_cast<const float4*>(&ALPHA[(size_t)(p0 + e) * NH]);
            float4 w1 = *reinterpret_cast<const float4*>(&ALPHA[(size_t)(p0 + e) * NH + 4]);
            w0.x *= den[0]; w0.y *= den[1]; w0.z *= den[2]; w0.w *= den[3];
            w1.x *= den[4]; w1.y *= den[5]; w1.z *= den[6]; w1.w *= den[7];
            *reinterpret_cast<float4*>(&ALPHA[(size_t)(p0 + e) * NH])     = w0;
            *reinterpret_cast<float4*>(&ALPHA[(size_t)(p0 + e) * NH + 4]) = w1;
        }
    }
}

// ---------------- Per-node gather aggregation: one WAVE per node ----------------
// Pure weighted-gather: alpha precomputed+normalized. Lane owns 8 fp16
// channels (16B load); two wave halves = 2 edges in parallel; unroll 4.
template<bool FINAL>
__global__ __launch_bounds__(256) void aggregate(
    const _Float16* __restrict__ HFh, const float* __restrict__ ALPHA,
    const int* __restrict__ rp, const int* __restrict__ ssrc,
    const float* __restrict__ BIAS,
    _Float16* __restrict__ X2H,
    const float* __restrict__ WL, const float* __restrict__ BL,
    float* __restrict__ OUT) {

    const int tid  = threadIdx.x;
    const int lane = tid & 63;
    const int node = __builtin_amdgcn_readfirstlane(blockIdx.x * 4 + (tid >> 6));
    const int epar = lane >> 5;        // which edge of the pair
    const int cg   = lane & 31;        // channel group: owns channels cg*8..cg*8+7
    const int hh   = cg >> 2;          // head of these channels
    const int c8   = cg * 8;

    const int p0  = rp[node];
    const int deg = rp[node + 1] - p0;   // >= 1 (self-loop)

    float a0=0.f,a1=0.f,a2=0.f,a3=0.f,a4=0.f,a5=0.f,a6=0.f,a7=0.f;

#pragma unroll 4
    for (int e0 = 0; e0 < deg; e0 += 2) {
        const int  e   = e0 + epar;
        const bool act = e < deg;
        const int  idx = p0 + (act ? e : 0);
        const int  sa  = ssrc[idx];
        const float wr = ALPHA[(size_t)idx * NH + hh];
        const float w  = act ? wr : 0.f;
        const f16x8 hv = *reinterpret_cast<const f16x8*>(&HFh[(size_t)sa * FH + c8]);
        a0 = fmaf((float)hv[0], w, a0);
        a1 = fmaf((float)hv[1], w, a1);
        a2 = fmaf((float)hv[2], w, a2);
        a3 = fmaf((float)hv[3], w, a3);
        a4 = fmaf((float)hv[4], w, a4);
        a5 = fmaf((float)hv[5], w, a5);
        a6 = fmaf((float)hv[6], w, a6);
        a7 = fmaf((float)hv[7], w, a7);
    }

    a0 += __shfl_xor(a0, 32); a1 += __shfl_xor(a1, 32);
    a2 += __shfl_xor(a2, 32); a3 += __shfl_xor(a3, 32);
    a4 += __shfl_xor(a4, 32); a5 += __shfl_xor(a5, 32);
    a6 += __shfl_xor(a6, 32); a7 += __shfl_xor(a7, 32);

    const float4 b0 = *reinterpret_cast<const float4*>(&BIAS[c8]);
    const float4 b1 = *reinterpret_cast<const float4*>(&BIAS[c8 + 4]);
    float o[8];
    o[0] = a0 + b0.x; o[1] = a1 + b0.y; o[2] = a2 + b0.z; o[3] = a3 + b0.w;
    o[4] = a4 + b1.x; o[5] = a5 + b1.y; o[6] = a6 + b1.z; o[7] = a7 + b1.w;
#pragma unroll
    for (int j = 0; j < 8; ++j) o[j] = o[j] > 0.f ? o[j] : expm1f(o[j]);

    if (!FINAL) {
        // emit fp16 for the next GEMM (4 channels per half-wave)
        uint2 st;
        st.x = f2h2(o[epar * 4 + 0], o[epar * 4 + 1]);
        st.y = f2h2(o[epar * 4 + 2], o[epar * 4 + 3]);
        *reinterpret_cast<uint2*>(&X2H[(size_t)node * FH + c8 + epar * 4]) = st;
    } else {
        const float4 w0 = *reinterpret_cast<const float4*>(&WL[c8]);
        const float4 w1 = *reinterpret_cast<const float4*>(&WL[c8 + 4]);
        float pl = fmaf(o[0], w0.x, fmaf(o[1], w0.y, fmaf(o[2], w0.z, o[3] * w0.w)));
        pl = fmaf(o[4], w1.x, fmaf(o[5], w1.y, fmaf(o[6], w1.z, fmaf(o[7], w1.w, pl))));
#pragma unroll
        for (int off = 16; off >= 1; off >>= 1) pl += __shfl_xor(pl, off);
        if (lane == 0) OUT[node] = pl + BL[0];
    }
}

// ---------------- launch ----------------
extern "C" void kernel_launch(void* const* d_in, const int* in_sizes, int n_in,
                              void* d_out, int out_size, void* d_ws, size_t ws_size,
                              hipStream_t stream) {
    const float* x   = (const float*)d_in[0];
    const int*   ei  = (const int*)d_in[1];
    const float* W1  = (const float*)d_in[2];
    const float* a1s = (const float*)d_in[3];
    const float* a1d = (const float*)d_in[4];
    const float* b1  = (const float*)d_in[5];
    const float* W2  = (const float*)d_in[6];
    const float* a2s = (const float*)d_in[7];
    const float* a2d = (const float*)d_in[8];
    const float* b2  = (const float*)d_in[9];
    const float* Wl  = (const float*)d_in[10];
    const float* bl  = (const float*)d_in[11];
    float* out = (float*)d_out;

    char* w = (char*)d_ws;
    auto alloc = [&](size_t bytes) -> char* {
        char* p = w;
        w += (bytes + 255) & ~size_t(255);
        return p;
    };
    int*   counts = (int*)alloc((size_t)NNODES * 4);
    int*   rp     = (int*)alloc((size_t)(NNODES + 1) * 4);
    int*   cursor = (int*)alloc((size_t)NNODES * 4);
    int*   bsum   = (int*)alloc((size_t)NSB * 4);
    int*   ssrc   = (int*)alloc((size_t)TE * 4);
    float* alpha  = (float*)alloc((size_t)TE * NH * 4);
    _Float16* hfh = (_Float16*)alloc((size_t)NNODES * FH * 2);
    _Float16* x1h = (_Float16*)alloc((size_t)NNODES * 128 * 2);   // fp16 x (layer-1 A)
    _Float16* x2h = (_Float16*)alloc((size_t)NNODES * FH * 2);    // fp16 layer-2 A
    float* asb    = (float*)alloc((size_t)NNODES * NH * 4);
    float* adb    = (float*)alloc((size_t)NNODES * NH * 4);
    _Float16* w1t = (_Float16*)alloc((size_t)128 * 256 * 2);
    _Float16* w2t = (_Float16*)alloc((size_t)256 * 256 * 2);

    hipMemsetAsync(counts, 0, (size_t)NNODES * 4, stream);
    count_kernel<<<(TE + 255) / 256, 256, 0, stream>>>(ei, counts);
    scan1_kernel<<<NSB, 256, 0, stream>>>(counts, rp, bsum);
    scan2_kernel<<<1, 128, 0, stream>>>(bsum);
    scan3_kernel<<<NSB, 256, 0, stream>>>(rp, bsum, cursor);
    fill_kernel<<<(TE + 255) / 256, 256, 0, stream>>>(ei, cursor, ssrc);

    const int xq = NNODES * 128 / 4;
    cvt_x_kernel<<<(xq + 255) / 256, 256, 0, stream>>>(x, x1h, xq);
    cvtT_w<128><<<128, 256, 0, stream>>>(W1, w1t);
    cvtT_w<256><<<256, 256, 0, stream>>>(W2, w2t);

    const dim3 ggrid((NNODES + 127) / 128, 2);
    gemm_mfma<128><<<ggrid, 256, 0, stream>>>(x1h, w1t, a1s, a1d, hfh, asb, adb);
    alpha_kernel<<<NNODES / 4, 256, 0, stream>>>(asb, adb, rp, ssrc, alpha);
    aggregate<false><<<NNODES / 4, 256, 0, stream>>>(hfh, alpha, rp, ssrc, b1,
                                                     x2h, nullptr, nullptr, nullptr);
    gemm_mfma<256><<<ggrid, 256, 0, stream>>>(x2h, w2t, a2s, a2d, hfh, asb, adb);
    alpha_kernel<<<NNODES / 4, 256, 0, stream>>>(asb, adb, rp, ssrc, alpha);
    aggregate<true><<<NNODES / 4, 256, 0, stream>>>(hfh, alpha, rp, ssrc, b2,
                                                    nullptr, Wl, bl, out);
}

// Round 9
// 214.884 us; speedup vs baseline: 1.0101x; 1.0101x over previous
//
#include <hip/hip_runtime.h>
#include <hip/hip_bf16.h>

#define NNODES 30000
#define NEDGES 480000
#define TE (NEDGES + NNODES)   // edges incl. self-loops
#define FH 256                 // hidden width (H*C)
#define NH 8                   // heads
#define NSB ((NNODES + 255) / 256)   // scan blocks = 118

typedef unsigned short ushort_t;
typedef __attribute__((ext_vector_type(8))) _Float16 f16x8;
typedef __attribute__((ext_vector_type(2))) _Float16 f16x2;
typedef __attribute__((ext_vector_type(4))) float f32x4;

// ---------------- CSR build (dst-sorted src lists) ----------------
__global__ void zero_counts(int* __restrict__ c) {
    int i = blockIdx.x * 256 + threadIdx.x;
    if (i < NNODES) c[i] = 0;
}

__global__ void count_kernel(const int* __restrict__ ei, int* __restrict__ counts) {
    int e = blockIdx.x * 256 + threadIdx.x;
    if (e >= TE) return;
    int d = (e < NEDGES) ? ei[NEDGES + e] : (e - NEDGES);
    atomicAdd(&counts[d], 1);
}

// hierarchical scan: (1) per-block local exclusive scan + block sums
__global__ __launch_bounds__(256) void scan1_kernel(const int* __restrict__ counts,
                                                    int* __restrict__ rp,
                                                    int* __restrict__ bsum) {
    __shared__ int s[256];
    const int tid = threadIdx.x;
    const int i = blockIdx.x * 256 + tid;
    int v = (i < NNODES) ? counts[i] : 0;
    s[tid] = v;
    __syncthreads();
    for (int off = 1; off < 256; off <<= 1) {
        int t = (tid >= off) ? s[tid - off] : 0;
        __syncthreads();
        s[tid] += t;
        __syncthreads();
    }
    if (i < NNODES) rp[i] = s[tid] - v;          // local exclusive prefix
    if (tid == 255) bsum[blockIdx.x] = s[255];
}

// (2) scan the 118 block sums in place (exclusive)
__global__ __launch_bounds__(128) void scan2_kernel(int* __restrict__ bsum) {
    __shared__ int s[128];
    const int tid = threadIdx.x;
    int v = (tid < NSB) ? bsum[tid] : 0;
    s[tid] = v;
    __syncthreads();
    for (int off = 1; off < 128; off <<= 1) {
        int t = (tid >= off) ? s[tid - off] : 0;
        __syncthreads();
        s[tid] += t;
        __syncthreads();
    }
    if (tid < NSB) bsum[tid] = s[tid] - v;
}

// (3) add block offsets, fan out to rp/cursor
__global__ __launch_bounds__(256) void scan3_kernel(int* __restrict__ rp,
                                                    const int* __restrict__ bsum,
                                                    int* __restrict__ cursor) {
    const int i = blockIdx.x * 256 + threadIdx.x;
    if (i < NNODES) {
        int r = rp[i] + bsum[blockIdx.x];
        rp[i] = r;
        cursor[i] = r;
    }
    if (i == 0) rp[NNODES] = TE;   // total is a compile-time constant
}

__global__ void fill_kernel(const int* __restrict__ ei, int* __restrict__ cursor,
                            int* __restrict__ ssrc) {
    int e = blockIdx.x * 256 + threadIdx.x;
    if (e >= TE) return;
    int s, d;
    if (e < NEDGES) { s = ei[e]; d = ei[NEDGES + e]; }
    else            { s = e - NEDGES; d = s; }
    int pos = atomicAdd(&cursor[d], 1);
    ssrc[pos] = s;
}

// ---------------- fp16 helpers ----------------
__device__ __forceinline__ unsigned f2h2(float a, float b) {  // pack 2 floats
    f16x2 h;
    h.x = (_Float16)a;
    h.y = (_Float16)b;
    return __builtin_bit_cast(unsigned, h);
}
__device__ __forceinline__ float2 h2f2(unsigned u) {   // unpack 2 packed halves
    f16x2 h = __builtin_bit_cast(f16x2, u);
    return make_float2((float)h.x, (float)h.y);
}

// ---------------- prepass: fp32 -> fp16 ----------------
__global__ void cvt_x_kernel(const float* __restrict__ X,
                             _Float16* __restrict__ out, int nquads) {
    int i = blockIdx.x * 256 + threadIdx.x;
    if (i >= nquads) return;
    float4 v = *reinterpret_cast<const float4*>(&X[(size_t)i * 4]);
    uint2 st;
    st.x = f2h2(v.x, v.y);
    st.y = f2h2(v.z, v.w);
    *reinterpret_cast<uint2*>(&out[(size_t)i * 4]) = st;
}

// W [K][256] row-major -> Wt fp16 [256][K] (n-major)
template<int K>
__global__ void cvtT_w(const float* __restrict__ W, _Float16* __restrict__ t) {
    int idx = blockIdx.x * 256 + threadIdx.x;   // n fast -> coalesced read
    if (idx >= 256 * K) return;
    int n = idx & 255, k = idx >> 8;
    t[n * K + k] = (_Float16)W[idx];
}

// ---------------- fp16 MFMA GEMM (h = X @ W) + fused alpha dots ----------------
// BM=128 x BN=128, BK=32, 256 threads = 4 waves of 64x64 (4x4 frags 16x16x32).
template<int K>
__global__ __launch_bounds__(256) void gemm_mfma(
    const _Float16* __restrict__ A,  const _Float16* __restrict__ Bt,   // [M][K], [256][K]
    const float* __restrict__ ASRC, const float* __restrict__ ADST,
    _Float16* __restrict__ HFh, float* __restrict__ AS, float* __restrict__ AD) {

    constexpr int LDK = 40;   // pad: 80B row stride, 16B aligned chunks
    __shared__ _Float16 Ah[128][LDK], Bh[128][LDK];   // 20 KB total

    const int tid  = threadIdx.x;
    const int lane = tid & 63;
    const int wid  = tid >> 6;
    const int m0 = blockIdx.x * 128;
    const int n0 = blockIdx.y * 128;
    const int wm = (wid & 1) * 64, wn = (wid >> 1) * 64;
    const int q = lane >> 4;          // quarter-wave
    const int c = lane & 15;

    f32x4 acc[4][4];
#pragma unroll
    for (int mi = 0; mi < 4; ++mi)
#pragma unroll
        for (int ni = 0; ni < 4; ++ni) acc[mi][ni] = (f32x4){0.f, 0.f, 0.f, 0.f};

    for (int k0 = 0; k0 < K; k0 += 32) {
        __syncthreads();
#pragma unroll
        for (int rep = 0; rep < 2; ++rep) {
            int idx = tid + 256 * rep;          // 0..511
            int row = idx >> 2;                 // 0..127
            int ch  = (idx & 3) * 8;            // k-chunk of 8 halves
            int gr = m0 + row;
            uint4 v = make_uint4(0u, 0u, 0u, 0u);
            if (gr < NNODES)
                v = *reinterpret_cast<const uint4*>(&A[(size_t)gr * K + k0 + ch]);
            *reinterpret_cast<uint4*>(&Ah[row][ch]) = v;
            uint4 bv = *reinterpret_cast<const uint4*>(&Bt[(size_t)(n0 + row) * K + k0 + ch]);
            *reinterpret_cast<uint4*>(&Bh[row][ch]) = bv;
        }
        __syncthreads();

        const int koff = q * 8;
        f16x8 fa[4], fb[4];
#pragma unroll
        for (int mi = 0; mi < 4; ++mi)
            fa[mi] = *reinterpret_cast<const f16x8*>(&Ah[wm + mi * 16 + c][koff]);
#pragma unroll
        for (int ni = 0; ni < 4; ++ni)
            fb[ni] = *reinterpret_cast<const f16x8*>(&Bh[wn + ni * 16 + c][koff]);
#pragma unroll
        for (int mi = 0; mi < 4; ++mi)
#pragma unroll
            for (int ni = 0; ni < 4; ++ni)
                acc[mi][ni] = __builtin_amdgcn_mfma_f32_16x16x32_f16(fa[mi], fb[ni], acc[mi][ni], 0, 0, 0);
    }

    // ---- epilogue: h (fp16) stores + fused per-head alpha dots (fp32 acc) ----
    float as_v[4], ad_v[4];
#pragma unroll
    for (int ni = 0; ni < 4; ++ni) {
        as_v[ni] = ASRC[n0 + wn + ni * 16 + c];
        ad_v[ni] = ADST[n0 + wn + ni * 16 + c];
    }
    const int head0 = (n0 + wn) >> 5;   // this wave covers heads head0, head0+1

#pragma unroll
    for (int mi = 0; mi < 4; ++mi) {
#pragma unroll
        for (int j = 0; j < 4; ++j) {
            int row = m0 + wm + mi * 16 + q * 4 + j;
            bool ok = row < NNODES;
            if (ok) {
#pragma unroll
                for (int ni = 0; ni < 4; ++ni)
                    HFh[(size_t)row * FH + n0 + wn + ni * 16 + c] = (_Float16)acc[mi][ni][j];
            }
            float ps0 = acc[mi][0][j] * as_v[0] + acc[mi][1][j] * as_v[1];
            float ps1 = acc[mi][2][j] * as_v[2] + acc[mi][3][j] * as_v[3];
            float pd0 = acc[mi][0][j] * ad_v[0] + acc[mi][1][j] * ad_v[1];
            float pd1 = acc[mi][2][j] * ad_v[2] + acc[mi][3][j] * ad_v[3];
#pragma unroll
            for (int off = 8; off >= 1; off >>= 1) {
                ps0 += __shfl_xor(ps0, off);
                ps1 += __shfl_xor(ps1, off);
                pd0 += __shfl_xor(pd0, off);
                pd1 += __shfl_xor(pd1, off);
            }
            if (ok && c == 0) {
                AS[row * NH + head0]     = ps0;
                AS[row * NH + head0 + 1] = ps1;
                AD[row * NH + head0]     = pd0;
                AD[row * NH + head0 + 1] = pd1;
            }
        }
    }
}

// ---------------- per-edge normalized attention weights (fp16 out) ----------------
// One wave per node, one lane per edge (fast path deg<=64; generic 2-pass
// fallback). Stores alpha[pos][8] fp16 (16B/edge), pre-divided by the denom.
__global__ __launch_bounds__(256) void alpha_kernel(
    const float* __restrict__ AS, const float* __restrict__ AD,
    const int* __restrict__ rp, const int* __restrict__ ssrc,
    _Float16* __restrict__ ALPHA) {

    const int tid  = threadIdx.x;
    const int lane = tid & 63;
    const int node = __builtin_amdgcn_readfirstlane(blockIdx.x * 4 + (tid >> 6));

    const int p0  = rp[node];
    const int deg = rp[node + 1] - p0;   // >= 1 (self-loop)

    const float4 ad0 = *reinterpret_cast<const float4*>(&AD[node * NH]);
    const float4 ad1 = *reinterpret_cast<const float4*>(&AD[node * NH + 4]);

    if (deg <= 64) {
        float w[8];
#pragma unroll
        for (int h = 0; h < 8; ++h) w[h] = 0.f;
        if (lane < deg) {
            int s = ssrc[p0 + lane];
            float4 as0 = *reinterpret_cast<const float4*>(&AS[s * NH]);
            float4 as1 = *reinterpret_cast<const float4*>(&AS[s * NH + 4]);
            float sv[8] = {as0.x + ad0.x, as0.y + ad0.y, as0.z + ad0.z, as0.w + ad0.w,
                           as1.x + ad1.x, as1.y + ad1.y, as1.z + ad1.z, as1.w + ad1.w};
#pragma unroll
            for (int h = 0; h < 8; ++h) {
                float t = sv[h] > 0.f ? sv[h] : 0.2f * sv[h];
                w[h] = __expf(t);
            }
        }
        float den[8];
#pragma unroll
        for (int h = 0; h < 8; ++h) {
            den[h] = w[h];
#pragma unroll
            for (int off = 32; off >= 1; off >>= 1)
                den[h] += __shfl_xor(den[h], off);
            den[h] = 1.f / (den[h] + 1e-16f);
        }
        if (lane < deg) {
            uint4 st;
            st.x = f2h2(w[0] * den[0], w[1] * den[1]);
            st.y = f2h2(w[2] * den[2], w[3] * den[3]);
            st.z = f2h2(w[4] * den[4], w[5] * den[5]);
            st.w = f2h2(w[6] * den[6], w[7] * den[7]);
            *reinterpret_cast<uint4*>(&ALPHA[(size_t)(p0 + lane) * NH]) = st;
        }
    } else {
        // generic: pass 1 stores raw w (fp16) + accumulates den; pass 2 rescales
        float den[8];
#pragma unroll
        for (int h = 0; h < 8; ++h) den[h] = 0.f;
        for (int e = lane; e < deg; e += 64) {
            int s = ssrc[p0 + e];
            float4 as0 = *reinterpret_cast<const float4*>(&AS[s * NH]);
            float4 as1 = *reinterpret_cast<const float4*>(&AS[s * NH + 4]);
            float sv[8] = {as0.x + ad0.x, as0.y + ad0.y, as0.z + ad0.z, as0.w + ad0.w,
                           as1.x + ad1.x, as1.y + ad1.y, as1.z + ad1.z, as1.w + ad1.w};
            float w[8];
#pragma unroll
            for (int h = 0; h < 8; ++h) {
                float t = sv[h] > 0.f ? sv[h] : 0.2f * sv[h];
                w[h] = __expf(t);
                den[h] += w[h];
            }
            uint4 st;
            st.x = f2h2(w[0], w[1]);
            st.y = f2h2(w[2], w[3]);
            st.z = f2h2(w[4], w[5]);
            st.w = f2h2(w[6], w[7]);
            *reinterpret_cast<uint4*>(&ALPHA[(size_t)(p0 + e) * NH]) = st;
        }
#pragma unroll
        for (int h = 0; h < 8; ++h) {
#pragma unroll
            for (int off = 32; off >= 1; off >>= 1)
                den[h] += __shfl_xor(den[h], off);
            den[h] = 1.f / (den[h] + 1e-16f);
        }
        for (int e = lane; e < deg; e += 64) {
            uint4 wv = *reinterpret_cast<const uint4*>(&ALPHA[(size_t)(p0 + e) * NH]);
            float2 c0 = h2f2(wv.x), c1 = h2f2(wv.y), c2 = h2f2(wv.z), c3 = h2f2(wv.w);
            uint4 st;
            st.x = f2h2(c0.x * den[0], c0.y * den[1]);
            st.y = f2h2(c1.x * den[2], c1.y * den[3]);
            st.z = f2h2(c2.x * den[4], c2.y * den[5]);
            st.w = f2h2(c3.x * den[6], c3.y * den[7]);
            *reinterpret_cast<uint4*>(&ALPHA[(size_t)(p0 + e) * NH]) = st;
        }
    }
}

// ---------------- Per-node gather aggregation: one WAVE per node ----------------
// Pure weighted-gather: alpha precomputed+normalized (fp16). Lane owns 8 fp16
// channels (16B load); two wave halves = 2 edges in parallel; unroll 4.
template<bool FINAL>
__global__ __launch_bounds__(256) void aggregate(
    const _Float16* __restrict__ HFh, const _Float16* __restrict__ ALPHA,
    const int* __restrict__ rp, const int* __restrict__ ssrc,
    const float* __restrict__ BIAS,
    _Float16* __restrict__ X2H,
    const float* __restrict__ WL, const float* __restrict__ BL,
    float* __restrict__ OUT) {

    const int tid  = threadIdx.x;
    const int lane = tid & 63;
    const int node = __builtin_amdgcn_readfirstlane(blockIdx.x * 4 + (tid >> 6));
    const int epar = lane >> 5;        // which edge of the pair
    const int cg   = lane & 31;        // channel group: owns channels cg*8..cg*8+7
    const int hh   = cg >> 2;          // head of these channels
    const int c8   = cg * 8;

    const int p0  = rp[node];
    const int deg = rp[node + 1] - p0;   // >= 1 (self-loop)

    float a0=0.f,a1=0.f,a2=0.f,a3=0.f,a4=0.f,a5=0.f,a6=0.f,a7=0.f;

#pragma unroll 4
    for (int e0 = 0; e0 < deg; e0 += 2) {
        const int  e   = e0 + epar;
        const bool act = e < deg;
        const int  idx = p0 + (act ? e : 0);
        const int  sa  = ssrc[idx];
        const float wr = (float)ALPHA[(size_t)idx * NH + hh];
        const float w  = act ? wr : 0.f;
        const f16x8 hv = *reinterpret_cast<const f16x8*>(&HFh[(size_t)sa * FH + c8]);
        a0 = fmaf((float)hv[0], w, a0);
        a1 = fmaf((float)hv[1], w, a1);
        a2 = fmaf((float)hv[2], w, a2);
        a3 = fmaf((float)hv[3], w, a3);
        a4 = fmaf((float)hv[4], w, a4);
        a5 = fmaf((float)hv[5], w, a5);
        a6 = fmaf((float)hv[6], w, a6);
        a7 = fmaf((float)hv[7], w, a7);
    }

    a0 += __shfl_xor(a0, 32); a1 += __shfl_xor(a1, 32);
    a2 += __shfl_xor(a2, 32); a3 += __shfl_xor(a3, 32);
    a4 += __shfl_xor(a4, 32); a5 += __shfl_xor(a5, 32);
    a6 += __shfl_xor(a6, 32); a7 += __shfl_xor(a7, 32);

    const float4 b0 = *reinterpret_cast<const float4*>(&BIAS[c8]);
    const float4 b1 = *reinterpret_cast<const float4*>(&BIAS[c8 + 4]);
    float o[8];
    o[0] = a0 + b0.x; o[1] = a1 + b0.y; o[2] = a2 + b0.z; o[3] = a3 + b0.w;
    o[4] = a4 + b1.x; o[5] = a5 + b1.y; o[6] = a6 + b1.z; o[7] = a7 + b1.w;
#pragma unroll
    for (int j = 0; j < 8; ++j) o[j] = o[j] > 0.f ? o[j] : expm1f(o[j]);

    if (!FINAL) {
        // emit fp16 for the next GEMM (4 channels per half-wave)
        uint2 st;
        st.x = f2h2(o[epar * 4 + 0], o[epar * 4 + 1]);
        st.y = f2h2(o[epar * 4 + 2], o[epar * 4 + 3]);
        *reinterpret_cast<uint2*>(&X2H[(size_t)node * FH + c8 + epar * 4]) = st;
    } else {
        const float4 w0 = *reinterpret_cast<const float4*>(&WL[c8]);
        const float4 w1 = *reinterpret_cast<const float4*>(&WL[c8 + 4]);
        float pl = fmaf(o[0], w0.x, fmaf(o[1], w0.y, fmaf(o[2], w0.z, o[3] * w0.w)));
        pl = fmaf(o[4], w1.x, fmaf(o[5], w1.y, fmaf(o[6], w1.z, fmaf(o[7], w1.w, pl))));
#pragma unroll
        for (int off = 16; off >= 1; off >>= 1) pl += __shfl_xor(pl, off);
        if (lane == 0) OUT[node] = pl + BL[0];
    }
}

// ---------------- launch ----------------
extern "C" void kernel_launch(void* const* d_in, const int* in_sizes, int n_in,
                              void* d_out, int out_size, void* d_ws, size_t ws_size,
                              hipStream_t stream) {
    const float* x   = (const float*)d_in[0];
    const int*   ei  = (const int*)d_in[1];
    const float* W1  = (const float*)d_in[2];
    const float* a1s = (const float*)d_in[3];
    const float* a1d = (const float*)d_in[4];
    const float* b1  = (const float*)d_in[5];
    const float* W2  = (const float*)d_in[6];
    const float* a2s = (const float*)d_in[7];
    const float* a2d = (const float*)d_in[8];
    const float* b2  = (const float*)d_in[9];
    const float* Wl  = (const float*)d_in[10];
    const float* bl  = (const float*)d_in[11];
    float* out = (float*)d_out;

    char* w = (char*)d_ws;
    auto alloc = [&](size_t bytes) -> char* {
        char* p = w;
        w += (bytes + 255) & ~size_t(255);
        return p;
    };
    int*   counts = (int*)alloc((size_t)NNODES * 4);
    int*   rp     = (int*)alloc((size_t)(NNODES + 1) * 4);
    int*   cursor = (int*)alloc((size_t)NNODES * 4);
    int*   bsum   = (int*)alloc((size_t)NSB * 4);
    int*   ssrc   = (int*)alloc((size_t)TE * 4);
    _Float16* alpha = (_Float16*)alloc((size_t)TE * NH * 2);
    _Float16* hfh = (_Float16*)alloc((size_t)NNODES * FH * 2);
    _Float16* x1h = (_Float16*)alloc((size_t)NNODES * 128 * 2);   // fp16 x (layer-1 A)
    _Float16* x2h = (_Float16*)alloc((size_t)NNODES * FH * 2);    // fp16 layer-2 A
    float* asb    = (float*)alloc((size_t)NNODES * NH * 4);
    float* adb    = (float*)alloc((size_t)NNODES * NH * 4);
    _Float16* w1t = (_Float16*)alloc((size_t)128 * 256 * 2);
    _Float16* w2t = (_Float16*)alloc((size_t)256 * 256 * 2);

    zero_counts<<<NSB, 256, 0, stream>>>(counts);
    count_kernel<<<(TE + 255) / 256, 256, 0, stream>>>(ei, counts);
    scan1_kernel<<<NSB, 256, 0, stream>>>(counts, rp, bsum);
    scan2_kernel<<<1, 128, 0, stream>>>(bsum);
    scan3_kernel<<<NSB, 256, 0, stream>>>(rp, bsum, cursor);
    fill_kernel<<<(TE + 255) / 256, 256, 0, stream>>>(ei, cursor, ssrc);

    const int xq = NNODES * 128 / 4;
    cvt_x_kernel<<<(xq + 255) / 256, 256, 0, stream>>>(x, x1h, xq);
    cvtT_w<128><<<128, 256, 0, stream>>>(W1, w1t);
    cvtT_w<256><<<256, 256, 0, stream>>>(W2, w2t);

    const dim3 ggrid((NNODES + 127) / 128, 2);
    gemm_mfma<128><<<ggrid, 256, 0, stream>>>(x1h, w1t, a1s, a1d, hfh, asb, adb);
    alpha_kernel<<<NNODES / 4, 256, 0, stream>>>(asb, adb, rp, ssrc, alpha);
    aggregate<false><<<NNODES / 4, 256, 0, stream>>>(hfh, alpha, rp, ssrc, b1,
                                                     x2h, nullptr, nullptr, nullptr);
    gemm_mfma<256><<<ggrid, 256, 0, stream>>>(x2h, w2t, a2s, a2d, hfh, asb, adb);
    alpha_kernel<<<NNODES / 4, 256, 0, stream>>>(asb, adb, rp, ssrc, alpha);
    aggregate<true><<<NNODES / 4, 256, 0, stream>>>(hfh, alpha, rp, ssrc, b2,
                                                    nullptr, Wl, bl, out);
}

// Round 10
// 199.749 us; speedup vs baseline: 1.0867x; 1.0758x over previous
//
#include <hip/hip_runtime.h>
#include <hip/hip_bf16.h>

#define NNODES 30000
#define NEDGES 480000
#define TE (NEDGES + NNODES)   // edges incl. self-loops
#define FH 256                 // hidden width (H*C)
#define NH 8                   // heads
#define NSB ((NNODES + 255) / 256)   // scan blocks = 118

typedef unsigned short ushort_t;
typedef __attribute__((ext_vector_type(8))) _Float16 f16x8;
typedef __attribute__((ext_vector_type(2))) _Float16 f16x2;
typedef __attribute__((ext_vector_type(4))) float f32x4;

// ---------------- CSR build (dst-sorted src lists) ----------------
__global__ void zero_counts(int* __restrict__ c) {
    int i = blockIdx.x * 256 + threadIdx.x;
    if (i < NNODES) c[i] = 0;
}

__global__ void count_kernel(const int* __restrict__ ei, int* __restrict__ counts) {
    int e = blockIdx.x * 256 + threadIdx.x;
    if (e >= TE) return;
    int d = (e < NEDGES) ? ei[NEDGES + e] : (e - NEDGES);
    atomicAdd(&counts[d], 1);
}

// hierarchical scan: (1) per-block local exclusive scan + block sums
__global__ __launch_bounds__(256) void scan1_kernel(const int* __restrict__ counts,
                                                    int* __restrict__ rp,
                                                    int* __restrict__ bsum) {
    __shared__ int s[256];
    const int tid = threadIdx.x;
    const int i = blockIdx.x * 256 + tid;
    int v = (i < NNODES) ? counts[i] : 0;
    s[tid] = v;
    __syncthreads();
    for (int off = 1; off < 256; off <<= 1) {
        int t = (tid >= off) ? s[tid - off] : 0;
        __syncthreads();
        s[tid] += t;
        __syncthreads();
    }
    if (i < NNODES) rp[i] = s[tid] - v;          // local exclusive prefix
    if (tid == 255) bsum[blockIdx.x] = s[255];
}

// (2) scan the 118 block sums in place (exclusive)
__global__ __launch_bounds__(128) void scan2_kernel(int* __restrict__ bsum) {
    __shared__ int s[128];
    const int tid = threadIdx.x;
    int v = (tid < NSB) ? bsum[tid] : 0;
    s[tid] = v;
    __syncthreads();
    for (int off = 1; off < 128; off <<= 1) {
        int t = (tid >= off) ? s[tid - off] : 0;
        __syncthreads();
        s[tid] += t;
        __syncthreads();
    }
    if (tid < NSB) bsum[tid] = s[tid] - v;
}

// (3) add block offsets, fan out to rp/cursor
__global__ __launch_bounds__(256) void scan3_kernel(int* __restrict__ rp,
                                                    const int* __restrict__ bsum,
                                                    int* __restrict__ cursor) {
    const int i = blockIdx.x * 256 + threadIdx.x;
    if (i < NNODES) {
        int r = rp[i] + bsum[blockIdx.x];
        rp[i] = r;
        cursor[i] = r;
    }
    if (i == 0) rp[NNODES] = TE;   // total is a compile-time constant
}

__global__ void fill_kernel(const int* __restrict__ ei, int* __restrict__ cursor,
                            int* __restrict__ ssrc) {
    int e = blockIdx.x * 256 + threadIdx.x;
    if (e >= TE) return;
    int s, d;
    if (e < NEDGES) { s = ei[e]; d = ei[NEDGES + e]; }
    else            { s = e - NEDGES; d = s; }
    int pos = atomicAdd(&cursor[d], 1);
    ssrc[pos] = s;
}

// ---------------- fp16 helpers ----------------
__device__ __forceinline__ unsigned f2h2(float a, float b) {  // pack 2 floats
    f16x2 h;
    h.x = (_Float16)a;
    h.y = (_Float16)b;
    return __builtin_bit_cast(unsigned, h);
}

// ---------------- prepass: fp32 -> fp16 ----------------
__global__ void cvt_x_kernel(const float* __restrict__ X,
                             _Float16* __restrict__ out, int nquads) {
    int i = blockIdx.x * 256 + threadIdx.x;
    if (i >= nquads) return;
    float4 v = *reinterpret_cast<const float4*>(&X[(size_t)i * 4]);
    uint2 st;
    st.x = f2h2(v.x, v.y);
    st.y = f2h2(v.z, v.w);
    *reinterpret_cast<uint2*>(&out[(size_t)i * 4]) = st;
}

// W [K][256] row-major -> Wt fp16 [256][K] (n-major)
template<int K>
__global__ void cvtT_w(const float* __restrict__ W, _Float16* __restrict__ t) {
    int idx = blockIdx.x * 256 + threadIdx.x;   // n fast -> coalesced read
    if (idx >= 256 * K) return;
    int n = idx & 255, k = idx >> 8;
    t[n * K + k] = (_Float16)W[idx];
}

// ---------------- fp16 MFMA GEMM (h = X @ W) + fused alpha dots ----------------
// BM=128 x BN=128, BK=32, 256 threads = 4 waves of 64x64 (4x4 frags 16x16x32).
template<int K>
__global__ __launch_bounds__(256) void gemm_mfma(
    const _Float16* __restrict__ A,  const _Float16* __restrict__ Bt,   // [M][K], [256][K]
    const float* __restrict__ ASRC, const float* __restrict__ ADST,
    _Float16* __restrict__ HFh, float* __restrict__ AS, float* __restrict__ AD) {

    constexpr int LDK = 40;   // pad: 80B row stride, 16B aligned chunks
    __shared__ _Float16 Ah[128][LDK], Bh[128][LDK];   // 20 KB total

    const int tid  = threadIdx.x;
    const int lane = tid & 63;
    const int wid  = tid >> 6;
    const int m0 = blockIdx.x * 128;
    const int n0 = blockIdx.y * 128;
    const int wm = (wid & 1) * 64, wn = (wid >> 1) * 64;
    const int q = lane >> 4;          // quarter-wave
    const int c = lane & 15;

    f32x4 acc[4][4];
#pragma unroll
    for (int mi = 0; mi < 4; ++mi)
#pragma unroll
        for (int ni = 0; ni < 4; ++ni) acc[mi][ni] = (f32x4){0.f, 0.f, 0.f, 0.f};

    for (int k0 = 0; k0 < K; k0 += 32) {
        __syncthreads();
#pragma unroll
        for (int rep = 0; rep < 2; ++rep) {
            int idx = tid + 256 * rep;          // 0..511
            int row = idx >> 2;                 // 0..127
            int ch  = (idx & 3) * 8;            // k-chunk of 8 halves
            int gr = m0 + row;
            uint4 v = make_uint4(0u, 0u, 0u, 0u);
            if (gr < NNODES)
                v = *reinterpret_cast<const uint4*>(&A[(size_t)gr * K + k0 + ch]);
            *reinterpret_cast<uint4*>(&Ah[row][ch]) = v;
            uint4 bv = *reinterpret_cast<const uint4*>(&Bt[(size_t)(n0 + row) * K + k0 + ch]);
            *reinterpret_cast<uint4*>(&Bh[row][ch]) = bv;
        }
        __syncthreads();

        const int koff = q * 8;
        f16x8 fa[4], fb[4];
#pragma unroll
        for (int mi = 0; mi < 4; ++mi)
            fa[mi] = *reinterpret_cast<const f16x8*>(&Ah[wm + mi * 16 + c][koff]);
#pragma unroll
        for (int ni = 0; ni < 4; ++ni)
            fb[ni] = *reinterpret_cast<const f16x8*>(&Bh[wn + ni * 16 + c][koff]);
#pragma unroll
        for (int mi = 0; mi < 4; ++mi)
#pragma unroll
            for (int ni = 0; ni < 4; ++ni)
                acc[mi][ni] = __builtin_amdgcn_mfma_f32_16x16x32_f16(fa[mi], fb[ni], acc[mi][ni], 0, 0, 0);
    }

    // ---- epilogue: h (fp16) stores + fused per-head alpha dots (fp32 acc) ----
    float as_v[4], ad_v[4];
#pragma unroll
    for (int ni = 0; ni < 4; ++ni) {
        as_v[ni] = ASRC[n0 + wn + ni * 16 + c];
        ad_v[ni] = ADST[n0 + wn + ni * 16 + c];
    }
    const int head0 = (n0 + wn) >> 5;   // this wave covers heads head0, head0+1

#pragma unroll
    for (int mi = 0; mi < 4; ++mi) {
#pragma unroll
        for (int j = 0; j < 4; ++j) {
            int row = m0 + wm + mi * 16 + q * 4 + j;
            bool ok = row < NNODES;
            if (ok) {
#pragma unroll
                for (int ni = 0; ni < 4; ++ni)
                    HFh[(size_t)row * FH + n0 + wn + ni * 16 + c] = (_Float16)acc[mi][ni][j];
            }
            float ps0 = acc[mi][0][j] * as_v[0] + acc[mi][1][j] * as_v[1];
            float ps1 = acc[mi][2][j] * as_v[2] + acc[mi][3][j] * as_v[3];
            float pd0 = acc[mi][0][j] * ad_v[0] + acc[mi][1][j] * ad_v[1];
            float pd1 = acc[mi][2][j] * ad_v[2] + acc[mi][3][j] * ad_v[3];
#pragma unroll
            for (int off = 8; off >= 1; off >>= 1) {
                ps0 += __shfl_xor(ps0, off);
                ps1 += __shfl_xor(ps1, off);
                pd0 += __shfl_xor(pd0, off);
                pd1 += __shfl_xor(pd1, off);
            }
            if (ok && c == 0) {
                AS[row * NH + head0]     = ps0;
                AS[row * NH + head0 + 1] = ps1;
                AD[row * NH + head0]     = pd0;
                AD[row * NH + head0 + 1] = pd1;
            }
        }
    }
}

// ---------------- Fused softmax + gather aggregation: one WAVE per node -------
// 64-edge chunks. Phase A (lane = edge): compute unnormalized w[8] once per
// edge, stash in this wave's LDS slab (stride 9 -> conflict-free). Wave-local
// ordering via s_waitcnt lgkmcnt(0) -- NO __syncthreads (divergent trip
// counts across waves; each wave owns its slab). Phase B (half-wave = edge):
// 512B h-row gather + LDS w read; acc and den accumulate; one divide at end.
template<bool FINAL>
__global__ __launch_bounds__(256) void aggregate(
    const _Float16* __restrict__ HFh,
    const float* __restrict__ AS, const float* __restrict__ AD,
    const int* __restrict__ rp, const int* __restrict__ ssrc,
    const float* __restrict__ BIAS,
    _Float16* __restrict__ X2H,
    const float* __restrict__ WL, const float* __restrict__ BL,
    float* __restrict__ OUT) {

    __shared__ float wslab[4][64 * 9];   // 9.2 KB; per-wave private slab

    const int tid  = threadIdx.x;
    const int lane = tid & 63;
    const int wid  = tid >> 6;
    const int node = __builtin_amdgcn_readfirstlane(blockIdx.x * 4 + wid);
    const int epar = lane >> 5;        // which edge of the pair (phase B)
    const int cg   = lane & 31;        // channel group: owns channels cg*8..cg*8+7
    const int hh   = cg >> 2;          // head of these channels
    const int c8   = cg * 8;
    float* wl = wslab[wid];

    const int p0  = rp[node];
    const int deg = rp[node + 1] - p0;   // >= 1 (self-loop)

    const float4 ad0 = *reinterpret_cast<const float4*>(&AD[node * NH]);
    const float4 ad1 = *reinterpret_cast<const float4*>(&AD[node * NH + 4]);

    float a0=0.f,a1=0.f,a2=0.f,a3=0.f,a4=0.f,a5=0.f,a6=0.f,a7=0.f;
    float den = 0.f;

    for (int base = 0; base < deg; base += 64) {
        const int ne = min(64, deg - base);

        // ---- phase A: lane e computes unnormalized w[8] for edge base+e ----
        if (lane < ne) {
            int s = ssrc[p0 + base + lane];
            float4 as0 = *reinterpret_cast<const float4*>(&AS[s * NH]);
            float4 as1 = *reinterpret_cast<const float4*>(&AS[s * NH + 4]);
            float sv[8] = {as0.x + ad0.x, as0.y + ad0.y, as0.z + ad0.z, as0.w + ad0.w,
                           as1.x + ad1.x, as1.y + ad1.y, as1.z + ad1.z, as1.w + ad1.w};
            float* wp = &wl[lane * 9];
#pragma unroll
            for (int h = 0; h < 8; ++h) {
                float t = sv[h] > 0.f ? sv[h] : 0.2f * sv[h];
                wp[h] = __expf(t);
            }
        }
        // wave-local LDS producer->consumer ordering (same wave, no barrier)
        asm volatile("s_waitcnt lgkmcnt(0)" ::: "memory");

        // ---- phase B: half-waves gather h rows, weight from LDS ----
        for (int e0 = 0; e0 < ne; e0 += 2) {
            const int  e   = e0 + epar;
            const bool act = e < ne;
            const int  ee  = act ? e : 0;
            const int  sa  = ssrc[p0 + base + ee];
            const float wr = wl[ee * 9 + hh];
            const float w  = act ? wr : 0.f;
            den += w;
            const f16x8 hv = *reinterpret_cast<const f16x8*>(&HFh[(size_t)sa * FH + c8]);
            a0 = fmaf((float)hv[0], w, a0);
            a1 = fmaf((float)hv[1], w, a1);
            a2 = fmaf((float)hv[2], w, a2);
            a3 = fmaf((float)hv[3], w, a3);
            a4 = fmaf((float)hv[4], w, a4);
            a5 = fmaf((float)hv[5], w, a5);
            a6 = fmaf((float)hv[6], w, a6);
            a7 = fmaf((float)hv[7], w, a7);
        }
        // slab reused next chunk: phase-A writes ordered after these reads by
        // the lgkmcnt(0) above (DS ops within a wave; reads complete first)
    }

    // combine the two edge-parallel halves
    a0 += __shfl_xor(a0, 32); a1 += __shfl_xor(a1, 32);
    a2 += __shfl_xor(a2, 32); a3 += __shfl_xor(a3, 32);
    a4 += __shfl_xor(a4, 32); a5 += __shfl_xor(a5, 32);
    a6 += __shfl_xor(a6, 32); a7 += __shfl_xor(a7, 32);
    den += __shfl_xor(den, 32);

    const float inv = 1.f / (den + 1e-16f);
    const float4 b0 = *reinterpret_cast<const float4*>(&BIAS[c8]);
    const float4 b1 = *reinterpret_cast<const float4*>(&BIAS[c8 + 4]);
    float o[8];
    o[0] = fmaf(a0, inv, b0.x); o[1] = fmaf(a1, inv, b0.y);
    o[2] = fmaf(a2, inv, b0.z); o[3] = fmaf(a3, inv, b0.w);
    o[4] = fmaf(a4, inv, b1.x); o[5] = fmaf(a5, inv, b1.y);
    o[6] = fmaf(a6, inv, b1.z); o[7] = fmaf(a7, inv, b1.w);
#pragma unroll
    for (int j = 0; j < 8; ++j) o[j] = o[j] > 0.f ? o[j] : expm1f(o[j]);

    if (!FINAL) {
        // emit fp16 for the next GEMM (4 channels per half-wave)
        uint2 st;
        st.x = f2h2(o[epar * 4 + 0], o[epar * 4 + 1]);
        st.y = f2h2(o[epar * 4 + 2], o[epar * 4 + 3]);
        *reinterpret_cast<uint2*>(&X2H[(size_t)node * FH + c8 + epar * 4]) = st;
    } else {
        const float4 w0 = *reinterpret_cast<const float4*>(&WL[c8]);
        const float4 w1 = *reinterpret_cast<const float4*>(&WL[c8 + 4]);
        float pl = fmaf(o[0], w0.x, fmaf(o[1], w0.y, fmaf(o[2], w0.z, o[3] * w0.w)));
        pl = fmaf(o[4], w1.x, fmaf(o[5], w1.y, fmaf(o[6], w1.z, fmaf(o[7], w1.w, pl))));
#pragma unroll
        for (int off = 16; off >= 1; off >>= 1) pl += __shfl_xor(pl, off);
        if (lane == 0) OUT[node] = pl + BL[0];
    }
}

// ---------------- launch ----------------
extern "C" void kernel_launch(void* const* d_in, const int* in_sizes, int n_in,
                              void* d_out, int out_size, void* d_ws, size_t ws_size,
                              hipStream_t stream) {
    const float* x   = (const float*)d_in[0];
    const int*   ei  = (const int*)d_in[1];
    const float* W1  = (const float*)d_in[2];
    const float* a1s = (const float*)d_in[3];
    const float* a1d = (const float*)d_in[4];
    const float* b1  = (const float*)d_in[5];
    const float* W2  = (const float*)d_in[6];
    const float* a2s = (const float*)d_in[7];
    const float* a2d = (const float*)d_in[8];
    const float* b2  = (const float*)d_in[9];
    const float* Wl  = (const float*)d_in[10];
    const float* bl  = (const float*)d_in[11];
    float* out = (float*)d_out;

    char* w = (char*)d_ws;
    auto alloc = [&](size_t bytes) -> char* {
        char* p = w;
        w += (bytes + 255) & ~size_t(255);
        return p;
    };
    int*   counts = (int*)alloc((size_t)NNODES * 4);
    int*   rp     = (int*)alloc((size_t)(NNODES + 1) * 4);
    int*   cursor = (int*)alloc((size_t)NNODES * 4);
    int*   bsum   = (int*)alloc((size_t)NSB * 4);
    int*   ssrc   = (int*)alloc((size_t)TE * 4);
    _Float16* hfh = (_Float16*)alloc((size_t)NNODES * FH * 2);
    _Float16* x1h = (_Float16*)alloc((size_t)NNODES * 128 * 2);   // fp16 x (layer-1 A)
    _Float16* x2h = (_Float16*)alloc((size_t)NNODES * FH * 2);    // fp16 layer-2 A
    float* asb    = (float*)alloc((size_t)NNODES * NH * 4);
    float* adb    = (float*)alloc((size_t)NNODES * NH * 4);
    _Float16* w1t = (_Float16*)alloc((size_t)128 * 256 * 2);
    _Float16* w2t = (_Float16*)alloc((size_t)256 * 256 * 2);

    zero_counts<<<NSB, 256, 0, stream>>>(counts);
    count_kernel<<<(TE + 255) / 256, 256, 0, stream>>>(ei, counts);
    scan1_kernel<<<NSB, 256, 0, stream>>>(counts, rp, bsum);
    scan2_kernel<<<1, 128, 0, stream>>>(bsum);
    scan3_kernel<<<NSB, 256, 0, stream>>>(rp, bsum, cursor);
    fill_kernel<<<(TE + 255) / 256, 256, 0, stream>>>(ei, cursor, ssrc);

    const int xq = NNODES * 128 / 4;
    cvt_x_kernel<<<(xq + 255) / 256, 256, 0, stream>>>(x, x1h, xq);
    cvtT_w<128><<<128, 256, 0, stream>>>(W1, w1t);
    cvtT_w<256><<<256, 256, 0, stream>>>(W2, w2t);

    const dim3 ggrid((NNODES + 127) / 128, 2);
    gemm_mfma<128><<<ggrid, 256, 0, stream>>>(x1h, w1t, a1s, a1d, hfh, asb, adb);
    aggregate<false><<<NNODES / 4, 256, 0, stream>>>(hfh, asb, adb, rp, ssrc, b1,
                                                     x2h, nullptr, nullptr, nullptr);
    gemm_mfma<256><<<ggrid, 256, 0, stream>>>(x2h, w2t, a2s, a2d, hfh, asb, adb);
    aggregate<true><<<NNODES / 4, 256, 0, stream>>>(hfh, asb, adb, rp, ssrc, b2,
                                                    nullptr, Wl, bl, out);
}

// Round 11
// 180.355 us; speedup vs baseline: 1.2035x; 1.1075x over previous
//
#include <hip/hip_runtime.h>
#include <hip/hip_bf16.h>

#define NNODES 30000
#define NEDGES 480000
#define TE (NEDGES + NNODES)   // edges incl. self-loops
#define FH 256                 // hidden width (H*C)
#define NH 8                   // heads
#define NSB ((NNODES + 255) / 256)   // scan blocks = 118

typedef unsigned short ushort_t;
typedef __attribute__((ext_vector_type(8))) _Float16 f16x8;
typedef __attribute__((ext_vector_type(2))) _Float16 f16x2;
typedef __attribute__((ext_vector_type(4))) float f32x4;

// ---------------- CSR build (dst-sorted src lists) ----------------
__global__ void zero_counts(int* __restrict__ c) {
    int i = blockIdx.x * 256 + threadIdx.x;
    if (i < NNODES) c[i] = 0;
}

__global__ void count_kernel(const int* __restrict__ ei, int* __restrict__ counts) {
    int e = blockIdx.x * 256 + threadIdx.x;
    if (e >= TE) return;
    int d = (e < NEDGES) ? ei[NEDGES + e] : (e - NEDGES);
    atomicAdd(&counts[d], 1);
}

// hierarchical scan: (1) per-block local exclusive scan + block sums
__global__ __launch_bounds__(256) void scan1_kernel(const int* __restrict__ counts,
                                                    int* __restrict__ rp,
                                                    int* __restrict__ bsum) {
    __shared__ int s[256];
    const int tid = threadIdx.x;
    const int i = blockIdx.x * 256 + tid;
    int v = (i < NNODES) ? counts[i] : 0;
    s[tid] = v;
    __syncthreads();
    for (int off = 1; off < 256; off <<= 1) {
        int t = (tid >= off) ? s[tid - off] : 0;
        __syncthreads();
        s[tid] += t;
        __syncthreads();
    }
    if (i < NNODES) rp[i] = s[tid] - v;          // local exclusive prefix
    if (tid == 255) bsum[blockIdx.x] = s[255];
}

// (2) scan the 118 block sums in place (exclusive)
__global__ __launch_bounds__(128) void scan2_kernel(int* __restrict__ bsum) {
    __shared__ int s[128];
    const int tid = threadIdx.x;
    int v = (tid < NSB) ? bsum[tid] : 0;
    s[tid] = v;
    __syncthreads();
    for (int off = 1; off < 128; off <<= 1) {
        int t = (tid >= off) ? s[tid - off] : 0;
        __syncthreads();
        s[tid] += t;
        __syncthreads();
    }
    if (tid < NSB) bsum[tid] = s[tid] - v;
}

// (3) add block offsets, fan out to rp/cursor
__global__ __launch_bounds__(256) void scan3_kernel(int* __restrict__ rp,
                                                    const int* __restrict__ bsum,
                                                    int* __restrict__ cursor) {
    const int i = blockIdx.x * 256 + threadIdx.x;
    if (i < NNODES) {
        int r = rp[i] + bsum[blockIdx.x];
        rp[i] = r;
        cursor[i] = r;
    }
    if (i == 0) rp[NNODES] = TE;   // total is a compile-time constant
}

__global__ void fill_kernel(const int* __restrict__ ei, int* __restrict__ cursor,
                            int* __restrict__ ssrc) {
    int e = blockIdx.x * 256 + threadIdx.x;
    if (e >= TE) return;
    int s, d;
    if (e < NEDGES) { s = ei[e]; d = ei[NEDGES + e]; }
    else            { s = e - NEDGES; d = s; }
    int pos = atomicAdd(&cursor[d], 1);
    ssrc[pos] = s;
}

// ---------------- fp16 helpers ----------------
__device__ __forceinline__ unsigned f2h2(float a, float b) {  // pack 2 floats
    f16x2 h;
    h.x = (_Float16)a;
    h.y = (_Float16)b;
    return __builtin_bit_cast(unsigned, h);
}

// W [K][256] row-major -> Wt fp16 [256][K] (n-major)
template<int K>
__global__ void cvtT_w(const float* __restrict__ W, _Float16* __restrict__ t) {
    int idx = blockIdx.x * 256 + threadIdx.x;   // n fast -> coalesced read
    if (idx >= 256 * K) return;
    int n = idx & 255, k = idx >> 8;
    t[n * K + k] = (_Float16)W[idx];
}

// ---------------- fp16 MFMA GEMM (h = X @ W) + fused alpha dots ----------------
// BM=128 x BN=128, BK=32, 256 threads = 4 waves of 64x64 (4x4 frags 16x16x32).
// CVT=true: A is fp32 (the raw input x), converted to fp16 during staging.
template<int K, bool CVT>
__global__ __launch_bounds__(256) void gemm_mfma(
    const void* __restrict__ Araw,  const _Float16* __restrict__ Bt,   // [M][K], [256][K]
    const float* __restrict__ ASRC, const float* __restrict__ ADST,
    _Float16* __restrict__ HFh, float* __restrict__ AS, float* __restrict__ AD) {

    constexpr int LDK = 40;   // pad: 80B row stride, 16B aligned chunks
    __shared__ _Float16 Ah[128][LDK], Bh[128][LDK];   // 20 KB total

    const int tid  = threadIdx.x;
    const int lane = tid & 63;
    const int wid  = tid >> 6;
    const int m0 = blockIdx.x * 128;
    const int n0 = blockIdx.y * 128;
    const int wm = (wid & 1) * 64, wn = (wid >> 1) * 64;
    const int q = lane >> 4;          // quarter-wave
    const int c = lane & 15;

    f32x4 acc[4][4];
#pragma unroll
    for (int mi = 0; mi < 4; ++mi)
#pragma unroll
        for (int ni = 0; ni < 4; ++ni) acc[mi][ni] = (f32x4){0.f, 0.f, 0.f, 0.f};

    for (int k0 = 0; k0 < K; k0 += 32) {
        __syncthreads();
#pragma unroll
        for (int rep = 0; rep < 2; ++rep) {
            int idx = tid + 256 * rep;          // 0..511
            int row = idx >> 2;                 // 0..127
            int ch  = (idx & 3) * 8;            // k-chunk of 8 halves
            int gr = m0 + row;
            uint4 v = make_uint4(0u, 0u, 0u, 0u);
            if (gr < NNODES) {
                if (CVT) {
                    const float* Xf = (const float*)Araw;
                    float4 f0 = *reinterpret_cast<const float4*>(&Xf[(size_t)gr * K + k0 + ch]);
                    float4 f1 = *reinterpret_cast<const float4*>(&Xf[(size_t)gr * K + k0 + ch + 4]);
                    v.x = f2h2(f0.x, f0.y); v.y = f2h2(f0.z, f0.w);
                    v.z = f2h2(f1.x, f1.y); v.w = f2h2(f1.z, f1.w);
                } else {
                    const _Float16* Ah_g = (const _Float16*)Araw;
                    v = *reinterpret_cast<const uint4*>(&Ah_g[(size_t)gr * K + k0 + ch]);
                }
            }
            *reinterpret_cast<uint4*>(&Ah[row][ch]) = v;
            uint4 bv = *reinterpret_cast<const uint4*>(&Bt[(size_t)(n0 + row) * K + k0 + ch]);
            *reinterpret_cast<uint4*>(&Bh[row][ch]) = bv;
        }
        __syncthreads();

        const int koff = q * 8;
        f16x8 fa[4], fb[4];
#pragma unroll
        for (int mi = 0; mi < 4; ++mi)
            fa[mi] = *reinterpret_cast<const f16x8*>(&Ah[wm + mi * 16 + c][koff]);
#pragma unroll
        for (int ni = 0; ni < 4; ++ni)
            fb[ni] = *reinterpret_cast<const f16x8*>(&Bh[wn + ni * 16 + c][koff]);
#pragma unroll
        for (int mi = 0; mi < 4; ++mi)
#pragma unroll
            for (int ni = 0; ni < 4; ++ni)
                acc[mi][ni] = __builtin_amdgcn_mfma_f32_16x16x32_f16(fa[mi], fb[ni], acc[mi][ni], 0, 0, 0);
    }

    // ---- epilogue: h (fp16) stores + fused per-head alpha dots (fp32 acc) ----
    float as_v[4], ad_v[4];
#pragma unroll
    for (int ni = 0; ni < 4; ++ni) {
        as_v[ni] = ASRC[n0 + wn + ni * 16 + c];
        ad_v[ni] = ADST[n0 + wn + ni * 16 + c];
    }
    const int head0 = (n0 + wn) >> 5;   // this wave covers heads head0, head0+1

#pragma unroll
    for (int mi = 0; mi < 4; ++mi) {
#pragma unroll
        for (int j = 0; j < 4; ++j) {
            int row = m0 + wm + mi * 16 + q * 4 + j;
            bool ok = row < NNODES;
            if (ok) {
#pragma unroll
                for (int ni = 0; ni < 4; ++ni)
                    HFh[(size_t)row * FH + n0 + wn + ni * 16 + c] = (_Float16)acc[mi][ni][j];
            }
            float ps0 = acc[mi][0][j] * as_v[0] + acc[mi][1][j] * as_v[1];
            float ps1 = acc[mi][2][j] * as_v[2] + acc[mi][3][j] * as_v[3];
            float pd0 = acc[mi][0][j] * ad_v[0] + acc[mi][1][j] * ad_v[1];
            float pd1 = acc[mi][2][j] * ad_v[2] + acc[mi][3][j] * ad_v[3];
#pragma unroll
            for (int off = 8; off >= 1; off >>= 1) {
                ps0 += __shfl_xor(ps0, off);
                ps1 += __shfl_xor(ps1, off);
                pd0 += __shfl_xor(pd0, off);
                pd1 += __shfl_xor(pd1, off);
            }
            if (ok && c == 0) {
                AS[row * NH + head0]     = ps0;
                AS[row * NH + head0 + 1] = ps1;
                AD[row * NH + head0]     = pd0;
                AD[row * NH + head0 + 1] = pd1;
            }
        }
    }
}

// ---------------- Fused softmax + gather aggregation: one WAVE per node -------
// 64-edge chunks. Phase A (lane = edge): compute unnormalized w[8] once per
// edge + stash src index in the wave's LDS slab (stride 10 -> 8B-aligned b64
// writes, 2-way bank alias = free). Wave-local ordering via s_waitcnt
// lgkmcnt(0) -- NO __syncthreads (divergent trip counts across waves; each
// wave owns its slab; same-wave DS ops execute in order). Phase B (half-wave
// = edge, unroll 4): w + src from LDS, one 16B h load, 8 v_fma_mix; den
// accumulated alongside; single divide at the end (unnormalized-sum trick).
template<bool FINAL>
__global__ __launch_bounds__(256) void aggregate(
    const _Float16* __restrict__ HFh,
    const float* __restrict__ AS, const float* __restrict__ AD,
    const int* __restrict__ rp, const int* __restrict__ ssrc,
    const float* __restrict__ BIAS,
    _Float16* __restrict__ X2H,
    const float* __restrict__ WL, const float* __restrict__ BL,
    float* __restrict__ OUT) {

    __shared__ float wslab[4][64 * 10];   // 10.2 KB; per-wave private slab

    const int tid  = threadIdx.x;
    const int lane = tid & 63;
    const int wid  = tid >> 6;
    const int node = __builtin_amdgcn_readfirstlane(blockIdx.x * 4 + wid);
    const int epar = lane >> 5;        // which edge of the pair (phase B)
    const int cg   = lane & 31;        // channel group: owns channels cg*8..cg*8+7
    const int hh   = cg >> 2;          // head of these channels
    const int c8   = cg * 8;
    float* wl = wslab[wid];

    const int p0  = rp[node];
    const int deg = rp[node + 1] - p0;   // >= 1 (self-loop)

    const float4 ad0 = *reinterpret_cast<const float4*>(&AD[node * NH]);
    const float4 ad1 = *reinterpret_cast<const float4*>(&AD[node * NH + 4]);

    float a0=0.f,a1=0.f,a2=0.f,a3=0.f,a4=0.f,a5=0.f,a6=0.f,a7=0.f;
    float den = 0.f;

    for (int base = 0; base < deg; base += 64) {
        const int ne = min(64, deg - base);

        // ---- phase A: lane e computes w[8] + src for edge base+e ----
        if (lane < ne) {
            int s = ssrc[p0 + base + lane];
            float4 as0 = *reinterpret_cast<const float4*>(&AS[s * NH]);
            float4 as1 = *reinterpret_cast<const float4*>(&AS[s * NH + 4]);
            float sv[8] = {as0.x + ad0.x, as0.y + ad0.y, as0.z + ad0.z, as0.w + ad0.w,
                           as1.x + ad1.x, as1.y + ad1.y, as1.z + ad1.z, as1.w + ad1.w};
            float* wp = &wl[lane * 10];
#pragma unroll
            for (int h = 0; h < 8; ++h) {
                float t = sv[h] > 0.f ? sv[h] : 0.2f * sv[h];
                wp[h] = __expf(t);
            }
            wp[8] = __int_as_float(s);
        }
        // wave-local LDS producer->consumer ordering (same wave, no barrier)
        asm volatile("s_waitcnt lgkmcnt(0)" ::: "memory");

        // ---- phase B: half-waves gather h rows; w + src from LDS ----
#pragma unroll 4
        for (int e0 = 0; e0 < ne; e0 += 2) {
            const int  e   = e0 + epar;
            const bool act = e < ne;
            const int  ee  = act ? e : 0;
            const int  sa  = __float_as_int(wl[ee * 10 + 8]);
            const float wr = wl[ee * 10 + hh];
            const float w  = act ? wr : 0.f;
            den += w;
            const f16x8 hv = *reinterpret_cast<const f16x8*>(&HFh[(size_t)sa * FH + c8]);
            a0 = fmaf((float)hv[0], w, a0);
            a1 = fmaf((float)hv[1], w, a1);
            a2 = fmaf((float)hv[2], w, a2);
            a3 = fmaf((float)hv[3], w, a3);
            a4 = fmaf((float)hv[4], w, a4);
            a5 = fmaf((float)hv[5], w, a5);
            a6 = fmaf((float)hv[6], w, a6);
            a7 = fmaf((float)hv[7], w, a7);
        }
        // slab reused next chunk: same-wave DS ordering keeps reads-before-
        // next-writes; lgkmcnt(0) above fences each chunk's writes
    }

    // combine the two edge-parallel halves
    a0 += __shfl_xor(a0, 32); a1 += __shfl_xor(a1, 32);
    a2 += __shfl_xor(a2, 32); a3 += __shfl_xor(a3, 32);
    a4 += __shfl_xor(a4, 32); a5 += __shfl_xor(a5, 32);
    a6 += __shfl_xor(a6, 32); a7 += __shfl_xor(a7, 32);
    den += __shfl_xor(den, 32);

    const float inv = 1.f / (den + 1e-16f);
    const float4 b0 = *reinterpret_cast<const float4*>(&BIAS[c8]);
    const float4 b1 = *reinterpret_cast<const float4*>(&BIAS[c8 + 4]);
    float o[8];
    o[0] = fmaf(a0, inv, b0.x); o[1] = fmaf(a1, inv, b0.y);
    o[2] = fmaf(a2, inv, b0.z); o[3] = fmaf(a3, inv, b0.w);
    o[4] = fmaf(a4, inv, b1.x); o[5] = fmaf(a5, inv, b1.y);
    o[6] = fmaf(a6, inv, b1.z); o[7] = fmaf(a7, inv, b1.w);
#pragma unroll
    for (int j = 0; j < 8; ++j) o[j] = o[j] > 0.f ? o[j] : expm1f(o[j]);

    if (!FINAL) {
        // emit fp16 for the next GEMM (4 channels per half-wave)
        uint2 st;
        st.x = f2h2(o[epar * 4 + 0], o[epar * 4 + 1]);
        st.y = f2h2(o[epar * 4 + 2], o[epar * 4 + 3]);
        *reinterpret_cast<uint2*>(&X2H[(size_t)node * FH + c8 + epar * 4]) = st;
    } else {
        const float4 w0 = *reinterpret_cast<const float4*>(&WL[c8]);
        const float4 w1 = *reinterpret_cast<const float4*>(&WL[c8 + 4]);
        float pl = fmaf(o[0], w0.x, fmaf(o[1], w0.y, fmaf(o[2], w0.z, o[3] * w0.w)));
        pl = fmaf(o[4], w1.x, fmaf(o[5], w1.y, fmaf(o[6], w1.z, fmaf(o[7], w1.w, pl))));
#pragma unroll
        for (int off = 16; off >= 1; off >>= 1) pl += __shfl_xor(pl, off);
        if (lane == 0) OUT[node] = pl + BL[0];
    }
}

// ---------------- launch ----------------
extern "C" void kernel_launch(void* const* d_in, const int* in_sizes, int n_in,
                              void* d_out, int out_size, void* d_ws, size_t ws_size,
                              hipStream_t stream) {
    const float* x   = (const float*)d_in[0];
    const int*   ei  = (const int*)d_in[1];
    const float* W1  = (const float*)d_in[2];
    const float* a1s = (const float*)d_in[3];
    const float* a1d = (const float*)d_in[4];
    const float* b1  = (const float*)d_in[5];
    const float* W2  = (const float*)d_in[6];
    const float* a2s = (const float*)d_in[7];
    const float* a2d = (const float*)d_in[8];
    const float* b2  = (const float*)d_in[9];
    const float* Wl  = (const float*)d_in[10];
    const float* bl  = (const float*)d_in[11];
    float* out = (float*)d_out;

    char* w = (char*)d_ws;
    auto alloc = [&](size_t bytes) -> char* {
        char* p = w;
        w += (bytes + 255) & ~size_t(255);
        return p;
    };
    int*   counts = (int*)alloc((size_t)NNODES * 4);
    int*   rp     = (int*)alloc((size_t)(NNODES + 1) * 4);
    int*   cursor = (int*)alloc((size_t)NNODES * 4);
    int*   bsum   = (int*)alloc((size_t)NSB * 4);
    int*   ssrc   = (int*)alloc((size_t)TE * 4);
    _Float16* hfh = (_Float16*)alloc((size_t)NNODES * FH * 2);
    _Float16* x2h = (_Float16*)alloc((size_t)NNODES * FH * 2);    // fp16 layer-2 A
    float* asb    = (float*)alloc((size_t)NNODES * NH * 4);
    float* adb    = (float*)alloc((size_t)NNODES * NH * 4);
    _Float16* w1t = (_Float16*)alloc((size_t)128 * 256 * 2);
    _Float16* w2t = (_Float16*)alloc((size_t)256 * 256 * 2);

    zero_counts<<<NSB, 256, 0, stream>>>(counts);
    count_kernel<<<(TE + 255) / 256, 256, 0, stream>>>(ei, counts);
    scan1_kernel<<<NSB, 256, 0, stream>>>(counts, rp, bsum);
    scan2_kernel<<<1, 128, 0, stream>>>(bsum);
    scan3_kernel<<<NSB, 256, 0, stream>>>(rp, bsum, cursor);
    fill_kernel<<<(TE + 255) / 256, 256, 0, stream>>>(ei, cursor, ssrc);

    cvtT_w<128><<<128, 256, 0, stream>>>(W1, w1t);
    cvtT_w<256><<<256, 256, 0, stream>>>(W2, w2t);

    const dim3 ggrid((NNODES + 127) / 128, 2);
    gemm_mfma<128, true><<<ggrid, 256, 0, stream>>>(x, w1t, a1s, a1d, hfh, asb, adb);
    aggregate<false><<<NNODES / 4, 256, 0, stream>>>(hfh, asb, adb, rp, ssrc, b1,
                                                     x2h, nullptr, nullptr, nullptr);
    gemm_mfma<256, false><<<ggrid, 256, 0, stream>>>(x2h, w2t, a2s, a2d, hfh, asb, adb);
    aggregate<true><<<NNODES / 4, 256, 0, stream>>>(hfh, asb, adb, rp, ssrc, b2,
                                                    nullptr, Wl, bl, out);
}

// Round 12
// 179.508 us; speedup vs baseline: 1.2092x; 1.0047x over previous
//
#include <hip/hip_runtime.h>
#include <hip/hip_bf16.h>

#define NNODES 30000
#define NEDGES 480000
#define TE (NEDGES + NNODES)   // edges incl. self-loops
#define FH 256                 // hidden width (H*C)
#define NH 8                   // heads
#define NSB ((NNODES + 255) / 256)   // scan blocks = 118

typedef unsigned short ushort_t;
typedef __attribute__((ext_vector_type(8))) _Float16 f16x8;
typedef __attribute__((ext_vector_type(2))) _Float16 f16x2;
typedef __attribute__((ext_vector_type(4))) float f32x4;

// ---------------- CSR build (dst-sorted src lists) ----------------
__global__ void zero_counts(int* __restrict__ c) {
    int i = blockIdx.x * 256 + threadIdx.x;
    if (i < NNODES) c[i] = 0;
}

__global__ void count_kernel(const int* __restrict__ ei, int* __restrict__ counts) {
    int e = blockIdx.x * 256 + threadIdx.x;
    if (e >= TE) return;
    int d = (e < NEDGES) ? ei[NEDGES + e] : (e - NEDGES);
    atomicAdd(&counts[d], 1);
}

// hierarchical scan: (1) per-block local exclusive scan + block sums
__global__ __launch_bounds__(256) void scan1_kernel(const int* __restrict__ counts,
                                                    int* __restrict__ rp,
                                                    int* __restrict__ bsum) {
    __shared__ int s[256];
    const int tid = threadIdx.x;
    const int i = blockIdx.x * 256 + tid;
    int v = (i < NNODES) ? counts[i] : 0;
    s[tid] = v;
    __syncthreads();
    for (int off = 1; off < 256; off <<= 1) {
        int t = (tid >= off) ? s[tid - off] : 0;
        __syncthreads();
        s[tid] += t;
        __syncthreads();
    }
    if (i < NNODES) rp[i] = s[tid] - v;          // local exclusive prefix
    if (tid == 255) bsum[blockIdx.x] = s[255];
}

// (2) scan the 118 block sums in place (exclusive)
__global__ __launch_bounds__(128) void scan2_kernel(int* __restrict__ bsum) {
    __shared__ int s[128];
    const int tid = threadIdx.x;
    int v = (tid < NSB) ? bsum[tid] : 0;
    s[tid] = v;
    __syncthreads();
    for (int off = 1; off < 128; off <<= 1) {
        int t = (tid >= off) ? s[tid - off] : 0;
        __syncthreads();
        s[tid] += t;
        __syncthreads();
    }
    if (tid < NSB) bsum[tid] = s[tid] - v;
}

// (3) add block offsets, fan out to rp/cursor
__global__ __launch_bounds__(256) void scan3_kernel(int* __restrict__ rp,
                                                    const int* __restrict__ bsum,
                                                    int* __restrict__ cursor) {
    const int i = blockIdx.x * 256 + threadIdx.x;
    if (i < NNODES) {
        int r = rp[i] + bsum[blockIdx.x];
        rp[i] = r;
        cursor[i] = r;
    }
    if (i == 0) rp[NNODES] = TE;   // total is a compile-time constant
}

__global__ void fill_kernel(const int* __restrict__ ei, int* __restrict__ cursor,
                            int* __restrict__ ssrc) {
    int e = blockIdx.x * 256 + threadIdx.x;
    if (e >= TE) return;
    int s, d;
    if (e < NEDGES) { s = ei[e]; d = ei[NEDGES + e]; }
    else            { s = e - NEDGES; d = s; }
    int pos = atomicAdd(&cursor[d], 1);
    ssrc[pos] = s;
}

// ---------------- fp16 helpers ----------------
__device__ __forceinline__ unsigned f2h2(float a, float b) {  // pack 2 floats
    f16x2 h;
    h.x = (_Float16)a;
    h.y = (_Float16)b;
    return __builtin_bit_cast(unsigned, h);
}

// Both weights: W [K][256] row-major -> Wt fp16 [256][K] (n-major), one launch
__global__ void cvtT_w_both(const float* __restrict__ W1, const float* __restrict__ W2,
                            _Float16* __restrict__ t1, _Float16* __restrict__ t2) {
    int idx = blockIdx.x * 256 + threadIdx.x;
    if (idx < 128 * 256) {
        int n = idx & 255, k = idx >> 8;            // k in [0,128)
        t1[n * 128 + k] = (_Float16)W1[idx];
    }
    int j = idx - 128 * 256;
    if (j >= 0 && j < 256 * 256) {
        int n = j & 255, k = j >> 8;                // k in [0,256)
        t2[n * 256 + k] = (_Float16)W2[j];
    }
}

// ---------------- fp16 MFMA GEMM (h = X @ W) + fused alpha dots ----------------
// BM=128 x BN=256 (full width: A read ONCE), BK=32, 512 threads = 8 waves of
// 64x64 (4x4 frags 16x16x32). CVT=true: A is fp32, converted during staging.
template<int K, bool CVT>
__global__ __launch_bounds__(512) void gemm_mfma(
    const void* __restrict__ Araw,  const _Float16* __restrict__ Bt,   // [M][K], [256][K]
    const float* __restrict__ ASRC, const float* __restrict__ ADST,
    _Float16* __restrict__ HFh, float* __restrict__ AS, float* __restrict__ AD) {

    constexpr int LDK = 40;   // pad: 80B row stride, 16B aligned chunks
    __shared__ _Float16 Ah[128][LDK];   // 10 KB
    __shared__ _Float16 Bh[256][LDK];   // 20 KB

    const int tid  = threadIdx.x;
    const int lane = tid & 63;
    const int wid  = tid >> 6;          // 0..7
    const int m0 = blockIdx.x * 128;
    const int wm = (wid & 1) * 64;      // 0,64
    const int wn = (wid >> 1) * 64;     // 0,64,128,192
    const int q = lane >> 4;            // quarter-wave
    const int c = lane & 15;

    f32x4 acc[4][4];
#pragma unroll
    for (int mi = 0; mi < 4; ++mi)
#pragma unroll
        for (int ni = 0; ni < 4; ++ni) acc[mi][ni] = (f32x4){0.f, 0.f, 0.f, 0.f};

    for (int k0 = 0; k0 < K; k0 += 32) {
        __syncthreads();
        {   // ---- stage A: 128 rows x 32 halves = 512 units, 1 rep ----
            int row = tid >> 2;                 // 0..127
            int ch  = (tid & 3) * 8;            // k-chunk of 8 halves
            int gr = m0 + row;
            uint4 v = make_uint4(0u, 0u, 0u, 0u);
            if (gr < NNODES) {
                if (CVT) {
                    const float* Xf = (const float*)Araw;
                    float4 f0 = *reinterpret_cast<const float4*>(&Xf[(size_t)gr * K + k0 + ch]);
                    float4 f1 = *reinterpret_cast<const float4*>(&Xf[(size_t)gr * K + k0 + ch + 4]);
                    v.x = f2h2(f0.x, f0.y); v.y = f2h2(f0.z, f0.w);
                    v.z = f2h2(f1.x, f1.y); v.w = f2h2(f1.z, f1.w);
                } else {
                    const _Float16* Ah_g = (const _Float16*)Araw;
                    v = *reinterpret_cast<const uint4*>(&Ah_g[(size_t)gr * K + k0 + ch]);
                }
            }
            *reinterpret_cast<uint4*>(&Ah[row][ch]) = v;
        }
#pragma unroll
        for (int rep = 0; rep < 2; ++rep) {   // ---- stage B: 256 rows = 1024 units ----
            int idx = tid + 512 * rep;          // 0..1023
            int row = idx >> 2;                 // 0..255
            int ch  = (idx & 3) * 8;
            uint4 bv = *reinterpret_cast<const uint4*>(&Bt[(size_t)row * K + k0 + ch]);
            *reinterpret_cast<uint4*>(&Bh[row][ch]) = bv;
        }
        __syncthreads();

        const int koff = q * 8;
        f16x8 fa[4], fb[4];
#pragma unroll
        for (int mi = 0; mi < 4; ++mi)
            fa[mi] = *reinterpret_cast<const f16x8*>(&Ah[wm + mi * 16 + c][koff]);
#pragma unroll
        for (int ni = 0; ni < 4; ++ni)
            fb[ni] = *reinterpret_cast<const f16x8*>(&Bh[wn + ni * 16 + c][koff]);
#pragma unroll
        for (int mi = 0; mi < 4; ++mi)
#pragma unroll
            for (int ni = 0; ni < 4; ++ni)
                acc[mi][ni] = __builtin_amdgcn_mfma_f32_16x16x32_f16(fa[mi], fb[ni], acc[mi][ni], 0, 0, 0);
    }

    // ---- epilogue: h (fp16) stores + fused per-head alpha dots (fp32 acc) ----
    float as_v[4], ad_v[4];
#pragma unroll
    for (int ni = 0; ni < 4; ++ni) {
        as_v[ni] = ASRC[wn + ni * 16 + c];
        ad_v[ni] = ADST[wn + ni * 16 + c];
    }
    const int head0 = wn >> 5;   // this wave covers heads head0, head0+1

#pragma unroll
    for (int mi = 0; mi < 4; ++mi) {
#pragma unroll
        for (int j = 0; j < 4; ++j) {
            int row = m0 + wm + mi * 16 + q * 4 + j;
            bool ok = row < NNODES;
            if (ok) {
#pragma unroll
                for (int ni = 0; ni < 4; ++ni)
                    HFh[(size_t)row * FH + wn + ni * 16 + c] = (_Float16)acc[mi][ni][j];
            }
            float ps0 = acc[mi][0][j] * as_v[0] + acc[mi][1][j] * as_v[1];
            float ps1 = acc[mi][2][j] * as_v[2] + acc[mi][3][j] * as_v[3];
            float pd0 = acc[mi][0][j] * ad_v[0] + acc[mi][1][j] * ad_v[1];
            float pd1 = acc[mi][2][j] * ad_v[2] + acc[mi][3][j] * ad_v[3];
#pragma unroll
            for (int off = 8; off >= 1; off >>= 1) {
                ps0 += __shfl_xor(ps0, off);
                ps1 += __shfl_xor(ps1, off);
                pd0 += __shfl_xor(pd0, off);
                pd1 += __shfl_xor(pd1, off);
            }
            if (ok && c == 0) {
                AS[row * NH + head0]     = ps0;
                AS[row * NH + head0 + 1] = ps1;
                AD[row * NH + head0]     = pd0;
                AD[row * NH + head0 + 1] = pd1;
            }
        }
    }
}

// ---------------- Fused softmax + gather aggregation: one WAVE per node -------
// (unchanged from R11 -- measured at ~93% of the 6.3 TB/s effective-BW roofline)
template<bool FINAL>
__global__ __launch_bounds__(256) void aggregate(
    const _Float16* __restrict__ HFh,
    const float* __restrict__ AS, const float* __restrict__ AD,
    const int* __restrict__ rp, const int* __restrict__ ssrc,
    const float* __restrict__ BIAS,
    _Float16* __restrict__ X2H,
    const float* __restrict__ WL, const float* __restrict__ BL,
    float* __restrict__ OUT) {

    __shared__ float wslab[4][64 * 10];   // 10.2 KB; per-wave private slab

    const int tid  = threadIdx.x;
    const int lane = tid & 63;
    const int wid  = tid >> 6;
    const int node = __builtin_amdgcn_readfirstlane(blockIdx.x * 4 + wid);
    const int epar = lane >> 5;        // which edge of the pair (phase B)
    const int cg   = lane & 31;        // channel group: owns channels cg*8..cg*8+7
    const int hh   = cg >> 2;          // head of these channels
    const int c8   = cg * 8;
    float* wl = wslab[wid];

    const int p0  = rp[node];
    const int deg = rp[node + 1] - p0;   // >= 1 (self-loop)

    const float4 ad0 = *reinterpret_cast<const float4*>(&AD[node * NH]);
    const float4 ad1 = *reinterpret_cast<const float4*>(&AD[node * NH + 4]);

    float a0=0.f,a1=0.f,a2=0.f,a3=0.f,a4=0.f,a5=0.f,a6=0.f,a7=0.f;
    float den = 0.f;

    for (int base = 0; base < deg; base += 64) {
        const int ne = min(64, deg - base);

        // ---- phase A: lane e computes w[8] + src for edge base+e ----
        if (lane < ne) {
            int s = ssrc[p0 + base + lane];
            float4 as0 = *reinterpret_cast<const float4*>(&AS[s * NH]);
            float4 as1 = *reinterpret_cast<const float4*>(&AS[s * NH + 4]);
            float sv[8] = {as0.x + ad0.x, as0.y + ad0.y, as0.z + ad0.z, as0.w + ad0.w,
                           as1.x + ad1.x, as1.y + ad1.y, as1.z + ad1.z, as1.w + ad1.w};
            float* wp = &wl[lane * 10];
#pragma unroll
            for (int h = 0; h < 8; ++h) {
                float t = sv[h] > 0.f ? sv[h] : 0.2f * sv[h];
                wp[h] = __expf(t);
            }
            wp[8] = __int_as_float(s);
        }
        // wave-local LDS producer->consumer ordering (same wave, no barrier)
        asm volatile("s_waitcnt lgkmcnt(0)" ::: "memory");

        // ---- phase B: half-waves gather h rows; w + src from LDS ----
#pragma unroll 4
        for (int e0 = 0; e0 < ne; e0 += 2) {
            const int  e   = e0 + epar;
            const bool act = e < ne;
            const int  ee  = act ? e : 0;
            const int  sa  = __float_as_int(wl[ee * 10 + 8]);
            const float wr = wl[ee * 10 + hh];
            const float w  = act ? wr : 0.f;
            den += w;
            const f16x8 hv = *reinterpret_cast<const f16x8*>(&HFh[(size_t)sa * FH + c8]);
            a0 = fmaf((float)hv[0], w, a0);
            a1 = fmaf((float)hv[1], w, a1);
            a2 = fmaf((float)hv[2], w, a2);
            a3 = fmaf((float)hv[3], w, a3);
            a4 = fmaf((float)hv[4], w, a4);
            a5 = fmaf((float)hv[5], w, a5);
            a6 = fmaf((float)hv[6], w, a6);
            a7 = fmaf((float)hv[7], w, a7);
        }
    }

    // combine the two edge-parallel halves
    a0 += __shfl_xor(a0, 32); a1 += __shfl_xor(a1, 32);
    a2 += __shfl_xor(a2, 32); a3 += __shfl_xor(a3, 32);
    a4 += __shfl_xor(a4, 32); a5 += __shfl_xor(a5, 32);
    a6 += __shfl_xor(a6, 32); a7 += __shfl_xor(a7, 32);
    den += __shfl_xor(den, 32);

    const float inv = 1.f / (den + 1e-16f);
    const float4 b0 = *reinterpret_cast<const float4*>(&BIAS[c8]);
    const float4 b1 = *reinterpret_cast<const float4*>(&BIAS[c8 + 4]);
    float o[8];
    o[0] = fmaf(a0, inv, b0.x); o[1] = fmaf(a1, inv, b0.y);
    o[2] = fmaf(a2, inv, b0.z); o[3] = fmaf(a3, inv, b0.w);
    o[4] = fmaf(a4, inv, b1.x); o[5] = fmaf(a5, inv, b1.y);
    o[6] = fmaf(a6, inv, b1.z); o[7] = fmaf(a7, inv, b1.w);
#pragma unroll
    for (int j = 0; j < 8; ++j) o[j] = o[j] > 0.f ? o[j] : expm1f(o[j]);

    if (!FINAL) {
        // emit fp16 for the next GEMM (4 channels per half-wave)
        uint2 st;
        st.x = f2h2(o[epar * 4 + 0], o[epar * 4 + 1]);
        st.y = f2h2(o[epar * 4 + 2], o[epar * 4 + 3]);
        *reinterpret_cast<uint2*>(&X2H[(size_t)node * FH + c8 + epar * 4]) = st;
    } else {
        const float4 w0 = *reinterpret_cast<const float4*>(&WL[c8]);
        const float4 w1 = *reinterpret_cast<const float4*>(&WL[c8 + 4]);
        float pl = fmaf(o[0], w0.x, fmaf(o[1], w0.y, fmaf(o[2], w0.z, o[3] * w0.w)));
        pl = fmaf(o[4], w1.x, fmaf(o[5], w1.y, fmaf(o[6], w1.z, fmaf(o[7], w1.w, pl))));
#pragma unroll
        for (int off = 16; off >= 1; off >>= 1) pl += __shfl_xor(pl, off);
        if (lane == 0) OUT[node] = pl + BL[0];
    }
}

// ---------------- launch ----------------
extern "C" void kernel_launch(void* const* d_in, const int* in_sizes, int n_in,
                              void* d_out, int out_size, void* d_ws, size_t ws_size,
                              hipStream_t stream) {
    const float* x   = (const float*)d_in[0];
    const int*   ei  = (const int*)d_in[1];
    const float* W1  = (const float*)d_in[2];
    const float* a1s = (const float*)d_in[3];
    const float* a1d = (const float*)d_in[4];
    const float* b1  = (const float*)d_in[5];
    const float* W2  = (const float*)d_in[6];
    const float* a2s = (const float*)d_in[7];
    const float* a2d = (const float*)d_in[8];
    const float* b2  = (const float*)d_in[9];
    const float* Wl  = (const float*)d_in[10];
    const float* bl  = (const float*)d_in[11];
    float* out = (float*)d_out;

    char* w = (char*)d_ws;
    auto alloc = [&](size_t bytes) -> char* {
        char* p = w;
        w += (bytes + 255) & ~size_t(255);
        return p;
    };
    int*   counts = (int*)alloc((size_t)NNODES * 4);
    int*   rp     = (int*)alloc((size_t)(NNODES + 1) * 4);
    int*   cursor = (int*)alloc((size_t)NNODES * 4);
    int*   bsum   = (int*)alloc((size_t)NSB * 4);
    int*   ssrc   = (int*)alloc((size_t)TE * 4);
    _Float16* hfh = (_Float16*)alloc((size_t)NNODES * FH * 2);
    _Float16* x2h = (_Float16*)alloc((size_t)NNODES * FH * 2);    // fp16 layer-2 A
    float* asb    = (float*)alloc((size_t)NNODES * NH * 4);
    float* adb    = (float*)alloc((size_t)NNODES * NH * 4);
    _Float16* w1t = (_Float16*)alloc((size_t)128 * 256 * 2);
    _Float16* w2t = (_Float16*)alloc((size_t)256 * 256 * 2);

    zero_counts<<<NSB, 256, 0, stream>>>(counts);
    count_kernel<<<(TE + 255) / 256, 256, 0, stream>>>(ei, counts);
    scan1_kernel<<<NSB, 256, 0, stream>>>(counts, rp, bsum);
    scan2_kernel<<<1, 128, 0, stream>>>(bsum);
    scan3_kernel<<<NSB, 256, 0, stream>>>(rp, bsum, cursor);
    fill_kernel<<<(TE + 255) / 256, 256, 0, stream>>>(ei, cursor, ssrc);

    cvtT_w_both<<<(128 * 256 + 256 * 256 + 255) / 256, 256, 0, stream>>>(W1, W2, w1t, w2t);

    const int gblocks = (NNODES + 127) / 128;
    gemm_mfma<128, true><<<gblocks, 512, 0, stream>>>(x, w1t, a1s, a1d, hfh, asb, adb);
    aggregate<false><<<NNODES / 4, 256, 0, stream>>>(hfh, asb, adb, rp, ssrc, b1,
                                                     x2h, nullptr, nullptr, nullptr);
    gemm_mfma<256, false><<<gblocks, 512, 0, stream>>>(x2h, w2t, a2s, a2d, hfh, asb, adb);
    aggregate<true><<<NNODES / 4, 256, 0, stream>>>(hfh, asb, adb, rp, ssrc, b2,
                                                    nullptr, Wl, bl, out);
}